// Round 7
// baseline (288.203 us; speedup 1.0000x reference)
//
#include <hip/hip_runtime.h>
#include <math.h>

// DDSP-style Generator for MI355X.
// R1: split latency-bound k_heads -> 5 kernels. 407->246us.
// R3: split upconv monolith -> kmat/ups/conv. 246->228us.
// R5 diagnosis: all kernels <40us (harness 40us poison fills own the top-5), but
//     20 launches x ~8us serialization gap = launch-bound. Work sum ~68us.
// R6: collapse to 8 kernels by fusing along the dependency chain:
//     s0 = lin+ups4+conv | sN = ups+conv (x3) | s4n = finconv+instnorm |
//     mm12 = both 1x1 layers | afp = heads + shfl-scan prefix + (dc+ncon block) |
//     harm. P0g/segT relaid [osc][j] so scan-lane writes coalesce.
// R7: resubmit (infra failure on even rounds, no data).
// All dot products accumulate in fp64 (freq path has ~5e4 amplification into tail phase).

static constexpr double PI_D     = 3.14159265358979323846;
static constexpr double LOWEST_D = 40.0 / 11025.0;
static constexpr double RT2O2    = 0.70710678118654752440;  // cos(pi/4)

#define NB    32
#define NFRM  64
#define NSMP  16384

// ---- k_s0 : lin (B,128)@(128,512) -> reshape (B,128,4) -> ups 2x -> conv3 w0 + leaky ----
__global__ __launch_bounds__(256) void k_s0(const float* __restrict__ x,
    const float* __restrict__ lw, const float* __restrict__ lb,
    const float* __restrict__ w0, const float* __restrict__ b0,
    float* __restrict__ out) {
  int b = blockIdx.x, g = blockIdx.y;          // g: 0..3 -> 32 output channels
  int tid = threadIdx.x;
  __shared__ float xs[128];
  __shared__ float lin[512];
  __shared__ float u[1024];                    // 128 ch x 8
  if (tid < 128) xs[tid] = x[b*128 + tid];
  __syncthreads();
  {
    double a0 = 0.0, a1 = 0.0;
    for (int l = 0; l < 128; ++l) {
      double xv = (double)xs[l];
      a0 += xv * (double)lw[(size_t)l*512 + tid];
      a1 += xv * (double)lw[(size_t)l*512 + tid + 256];
    }
    lin[tid]     = (float)(a0 + (double)lb[tid]);
    lin[tid+256] = (float)(a1 + (double)lb[tid+256]);
  }
  __syncthreads();
  // ups4: exact band-limited 2x matrix, n=4 (cos table is exact constants)
  const double ct8[8] = {1.0, RT2O2, 0.0, -RT2O2, -1.0, -RT2O2, 0.0, RT2O2};
  #pragma unroll
  for (int rep = 0; rep < 4; ++rep) {
    int idx = tid + 256*rep;
    int c = idx >> 3, m = idx & 7;
    double cm2 = (m & 1) ? 0.0 : ((m & 2) ? -1.0 : 1.0);
    double a = 0.0;
    #pragma unroll
    for (int j = 0; j < 4; ++j) {
      double K = 0.25*(1.0 + 2.0*ct8[(m - 2*j) & 7] + 2.0*cm2*((j & 1) ? -1.0 : 1.0));
      a += K * (double)lin[c*4 + j];
    }
    u[idx] = (float)a;
  }
  __syncthreads();
  int ol = tid >> 3, t = tid & 7;              // 32 out-ch x 8 t
  int o = g*32 + ol;
  double a0 = 0.0, a1 = 0.0;
  const float* wp = w0 + (size_t)o*384;
  for (int c = 0; c < 128; ++c) {
    int base = c*8 + t;
    float xm = (t > 0) ? u[base-1] : 0.f;
    float xc = u[base];
    float xp = (t < 7) ? u[base+1] : 0.f;
    a0 += (double)wp[c*3+0]*(double)xm + (double)wp[c*3+1]*(double)xc;
    a1 += (double)wp[c*3+2]*(double)xp;
  }
  float v = (float)(a0 + a1 + (double)b0[o]);
  v = (v > 0.f) ? v : 0.2f*v;
  out[((size_t)b*128 + o)*8 + t] = v;
}

// ---- k_sN<TIN> : ups 2x (exact K in LDS, transposed) + conv3 + leaky ----
template<int TIN>
__global__ __launch_bounds__(256) void k_sN(const float* __restrict__ in,
    const float* __restrict__ w, const float* __restrict__ bias,
    float* __restrict__ out) {
  constexpr int T   = 2*TIN;
  constexpr int OCB = 256/T;                   // out channels per block
  int b = blockIdx.x, g = blockIdx.y;
  int tid = threadIdx.x;
  __shared__ float  ub[128*TIN];
  __shared__ float  uu[128*T];
  __shared__ double Kt[TIN*T];                 // [j][m] transposed -> conflict-free reads
  __shared__ double ctab[2*TIN];
  for (int i = tid; i < 128*TIN; i += 256) ub[i] = in[(size_t)b*128*TIN + i];
  for (int d = tid; d < 2*TIN; d += 256) ctab[d] = cos(PI_D*(double)d/(double)TIN);
  __syncthreads();
  for (int i = tid; i < TIN*T; i += 256) {
    int j = i / T, m = i - (i/T)*T;
    int dm = m - 2*j;
    double s = 1.0;
    #pragma unroll
    for (int k = 1; k <= TIN/2 - 1; ++k) s += 2.0*ctab[(k*dm) & (2*TIN - 1)];
    double cm2 = (m & 1) ? 0.0 : ((m & 2) ? -1.0 : 1.0);
    s += 2.0*cm2*((j & 1) ? -1.0 : 1.0);
    Kt[i] = s/(double)TIN;
  }
  __syncthreads();
  for (int i = tid; i < 128*T; i += 256) {     // u = K x, per output elem
    int c = i / T, m = i - (i/T)*T;
    double a = 0.0;
    #pragma unroll 4
    for (int j = 0; j < TIN; ++j) a += Kt[j*T + m] * (double)ub[c*TIN + j];
    uu[i] = (float)a;
  }
  __syncthreads();
  int ol = tid / T, t = tid % T;
  int o = g*OCB + ol;
  double a0 = 0.0, a1 = 0.0;
  const float* wp = w + (size_t)o*384;
  for (int c = 0; c < 128; ++c) {
    int base = c*T + t;
    float xm = (t > 0)   ? uu[base-1] : 0.f;
    float xc = uu[base];
    float xp = (t < T-1) ? uu[base+1] : 0.f;
    a0 += (double)wp[c*3+0]*(double)xm + (double)wp[c*3+1]*(double)xc;
    a1 += (double)wp[c*3+2]*(double)xp;
  }
  float v = (float)(a0 + a1 + (double)bias[o]);
  v = (v > 0.f) ? v : 0.2f*v;
  out[((size_t)b*128 + o)*T + t] = v;
}

// ---- k_s4n : final conv3 (128->64 ch, T=64, no act) + instance-norm (wave = channel) ----
__global__ __launch_bounds__(256) void k_s4n(const float* __restrict__ in,
    const float* __restrict__ fw, const float* __restrict__ fb,
    float* __restrict__ hnorm) {
  int b = blockIdx.x, g = blockIdx.y;          // g 0..15 -> 4 out channels
  int tid = threadIdx.x;
  __shared__ float uu[128*64];
  for (int i = tid; i < 128*64; i += 256) uu[i] = in[(size_t)b*8192 + i];
  __syncthreads();
  int ol = tid >> 6, t = tid & 63;
  int o = g*4 + ol;
  double a0 = 0.0, a1 = 0.0;
  const float* wp = fw + (size_t)o*384;        // wave-uniform -> scalar loads
  for (int c = 0; c < 128; ++c) {
    int base = c*64 + t;
    float xm = (t > 0)  ? uu[base-1] : 0.f;
    float xc = uu[base];
    float xp = (t < 63) ? uu[base+1] : 0.f;
    a0 += (double)wp[c*3+0]*(double)xm + (double)wp[c*3+1]*(double)xc;
    a1 += (double)wp[c*3+2]*(double)xp;
  }
  float vf = (float)(a0 + a1 + (double)fb[o]);
  double s = (double)vf;
  for (int off = 32; off > 0; off >>= 1) s += __shfl_down(s, off);
  double mean = __shfl(s, 0) * (1.0/64.0);
  double d = (double)vf - mean;
  double s2 = d*d;
  for (int off = 32; off > 0; off >>= 1) s2 += __shfl_down(s2, off);
  double var = __shfl(s2, 0) * (1.0/64.0);
  float sc = (float)(1.0 / sqrt(var + 1e-5));
  hnorm[((size_t)b*64 + o)*64 + t] = (float)d * sc;
}

// ---- k_mm12 : both 1x1-conv layers; block = (16 t-cols, b, chain z) ----
__global__ __launch_bounds__(256) void k_mm12(const float* __restrict__ hn,
    const float* __restrict__ hw1, const float* __restrict__ hb1,
    const float* __restrict__ hw2, const float* __restrict__ hb2,
    const float* __restrict__ tw1, const float* __restrict__ tb1,
    const float* __restrict__ tw2, const float* __restrict__ tb2,
    float* __restrict__ hh, float* __restrict__ nbuf) {
  int tq = blockIdx.x, b = blockIdx.y, z = blockIdx.z;
  int tid = threadIdx.x;
  const float* W1 = z ? tw1 : hw1; const float* B1 = z ? tb1 : hb1;
  const float* W2 = z ? tw2 : hw2; const float* B2 = z ? tb2 : hb2;
  __shared__ float h0[64*16];
  __shared__ float t1[64*16];
  for (int i = tid; i < 1024; i += 256) {
    int c = i >> 4, tt = i & 15;
    h0[i] = hn[((size_t)b*64 + c)*64 + tq*16 + tt];
  }
  __syncthreads();
  int t = tid & 15, ob = tid >> 4;             // ob 0..15, 4 o's per thread
  #pragma unroll
  for (int k = 0; k < 4; ++k) {
    int o = ob + 16*k;
    double a0 = 0.0, a1 = 0.0;
    const float* wp = W1 + o*64;
    for (int c = 0; c < 64; c += 2) {
      a0 += (double)wp[c]  *(double)h0[c*16 + t];
      a1 += (double)wp[c+1]*(double)h0[(c+1)*16 + t];
    }
    float v = (float)(a0 + a1 + (double)B1[o]);
    v = (v > 0.f) ? v : 0.2f*v;
    t1[o*16 + t] = v;
  }
  __syncthreads();
  float* out = z ? nbuf : hh;
  #pragma unroll
  for (int k = 0; k < 4; ++k) {
    int o = ob + 16*k;
    double a0 = 0.0, a1 = 0.0;
    const float* wp = W2 + o*64;
    for (int c = 0; c < 64; c += 2) {
      a0 += (double)wp[c]  *(double)t1[c*16 + t];
      a1 += (double)wp[c+1]*(double)t1[(c+1)*16 + t];
    }
    out[((size_t)b*64 + o)*64 + tq*16 + t] = (float)(a0 + a1 + (double)B2[o]);
  }
}

// ---- k_afp : amp/freq heads + shfl-scan prefix (g<32); dc+ncon (g==32) ----
// P0[j] = 64*(F_{j-1}+F_{j-2}) with F = inclusive lane-scan of f (fp64), F_{-1}=0.
// Layout: P0g/segT rows [b*128+osc]*65 + j  -> scan-lane writes are coalesced.
__global__ __launch_bounds__(256) void k_afp(const float* __restrict__ hh,
    const float* __restrict__ amp_w, const float* __restrict__ amp_b,
    const float* __restrict__ freq_w, const float* __restrict__ freq_b,
    const float* __restrict__ nbuf,
    const float* __restrict__ nm_w1, const float* __restrict__ nm_b1,
    const float* __restrict__ nm_w2, const float* __restrict__ nm_b2,
    const float* __restrict__ noise,
    double* __restrict__ P0g, float4* __restrict__ segT,
    float* __restrict__ ncon) {
  int g = blockIdx.x, b = blockIdx.y;
  int tid = threadIdx.x;
  if (g < 32) {
    int ow = tid >> 6;                         // wave -> oscillator
    int o = g*4 + ow;
    int lane = tid & 63;                       // frame j
    const float* X  = hh + (size_t)b*4096 + lane;
    const float* wa = amp_w + o*64;
    const float* wf = freq_w + o*64;
    double za = (double)amp_b[o], zf = (double)freq_b[o];
    for (int c = 0; c < 64; ++c) {
      double hv = (double)X[(size_t)c*64];
      za += (double)wa[c]*hv;
      zf += (double)wf[c]*hv;
    }
    float a = fabsf((float)za);
    double sg = 1.0/(1.0 + exp(-zf));
    float f = (float)(LOWEST_D + sg*sg*(1.0 - LOWEST_D));
    double F = (double)f;                      // inclusive scan over 64 lanes
    #pragma unroll
    for (int off = 1; off < 64; off <<= 1) {
      double n = __shfl_up(F, off);
      if (lane >= off) F += n;
    }
    double Fm1 = __shfl_up(F, 1); if (lane < 1) Fm1 = 0.0;
    double Fm2 = __shfl_up(F, 2); if (lane < 2) Fm2 = 0.0;
    float fm1 = __shfl_up(f, 1);
    float am1 = __shfl_up(a, 1);
    size_t row = ((size_t)b*128 + o)*65;
    P0g[row + lane] = (lane == 0) ? 0.0 : 64.0*(Fm1 + Fm2);
    segT[row + lane] = (lane == 0) ? make_float4(f, 0.f, a, 0.f)
                                   : make_float4(fm1, f - fm1, am1, a - am1);
    if (lane == 63) {
      P0g[row + 64]  = 64.0*(F + Fm1);
      segT[row + 64] = make_float4(f, 0.f, a, 0.f);
    }
  } else {
    __shared__ double veff[64];
    __shared__ double dcs[64];
    if (tid < 64) {                            // veff[m] = sum_c nm_w2[0,c]*nm_w1[c,m]
      double a = 0.0;
      for (int c = 0; c < 128; ++c) a += (double)nm_w2[c]*(double)nm_w1[c*64 + tid];
      veff[tid] = a;
    }
    double beff = (double)nm_b2[0];
    for (int c = 0; c < 128; ++c) beff += (double)nm_w2[c]*(double)nm_b1[c];
    int wv = tid >> 6, lane = tid & 63;
    for (int k = 0; k < 16; ++k) {             // dc of 16 frames per wave
      int fr = wv*16 + k;
      const float* p = noise + ((size_t)b*64 + fr)*512;
      double s = 0.0;
      for (int i = lane; i < 512; i += 64) s += (double)p[i];
      for (int off = 32; off > 0; off >>= 1) s += __shfl_down(s, off);
      if (lane == 0) dcs[fr] = s;
    }
    __syncthreads();
    if (tid < 64) {
      int fr = tid;
      double s0 = beff;
      for (int m = 0; m < 64; ++m) s0 += veff[m]*(double)nbuf[((size_t)b*64 + m)*64 + fr];
      ncon[b*64 + fr] = (float)(dcs[fr]*s0*(1.0/512.0));
    }
  }
}

// ---- k_harm : block = (q,b): 256 samples x 128 oscillators ----
// rev(s) = P0 + 0.5*[(r+1)*f_lo + ((r+1)*w0 + r(r+1)/512)*df], fract -> v_sin_f32.
__global__ __launch_bounds__(256) void k_harm(const double* __restrict__ P0g,
                                              const float4* __restrict__ segT,
                                              const float* __restrict__ nc,
                                              float* __restrict__ outp) {
  int q = blockIdx.x;                          // 0..63
  int b = blockIdx.y;
  int tid = threadIdx.x;
  __shared__ double P0s[256];                  // [half][osc]
  __shared__ float4 segs[256];
  int half = tid >> 7;
  int osc  = tid & 127;
  {
    size_t row = ((size_t)b*128 + osc)*65 + (q + half);
    P0s[tid]  = P0g[row];
    segs[tid] = segT[row];
  }
  __syncthreads();

  int j = q + half;
  int s = q*256 + tid;
  int r = (j == 0) ? s : (s - (256*j - 128));
  float w0 = (j == 0 || j == 64) ? 0.f : (1.f/512.f);
  double rp = (double)(r + 1);
  double c1 = rp * 0.5;
  double c2 = (rp*(double)w0 + (double)r*rp*(1.0/512.0)) * 0.5;
  float wr = w0 + (float)r*(1.f/256.f);

  const double* P0p = P0s + half*128;
  const float4* sp  = segs + half*128;
  float acc = 0.f;
  #pragma unroll 4
  for (int o = 0; o < 128; ++o) {
    float4 sg = sp[o];                         // {f_lo, df, a_lo, da}
    double rev = P0p[o] + c1*(double)sg.x + c2*(double)sg.y;
    rev -= floor(rev);
    float sv = __builtin_amdgcn_sinf((float)rev);   // sin(2*pi*x)
    float am = sg.z + sg.w*wr;
    acc = fmaf(sv, am, acc);
  }
  float ns = nc[b*NFRM + q] + ((q > 0) ? nc[b*NFRM + q - 1] : 0.f);
  outp[(size_t)b*NSMP + s] = acc + ns;
}

// ---------------------------------------------------------------------------
extern "C" void kernel_launch(void* const* d_in, const int* in_sizes, int n_in,
                              void* d_out, int out_size, void* d_ws, size_t ws_size,
                              hipStream_t stream) {
  (void)in_sizes; (void)n_in; (void)out_size; (void)ws_size;
  const float* x      = (const float*)d_in[0];
  const float* lin_w  = (const float*)d_in[1];
  const float* lin_b  = (const float*)d_in[2];
  const float* up_w0  = (const float*)d_in[3];
  const float* up_b0  = (const float*)d_in[4];
  const float* up_w1  = (const float*)d_in[5];
  const float* up_b1  = (const float*)d_in[6];
  const float* up_w2  = (const float*)d_in[7];
  const float* up_b2  = (const float*)d_in[8];
  const float* up_w3  = (const float*)d_in[9];
  const float* up_b3  = (const float*)d_in[10];
  const float* fin_w  = (const float*)d_in[11];
  const float* fin_b  = (const float*)d_in[12];
  const float* hw1    = (const float*)d_in[13];
  const float* hb1    = (const float*)d_in[14];
  const float* hw2    = (const float*)d_in[15];
  const float* hb2    = (const float*)d_in[16];
  const float* tw1    = (const float*)d_in[17];
  const float* tb1    = (const float*)d_in[18];
  const float* tw2    = (const float*)d_in[19];
  const float* tb2    = (const float*)d_in[20];
  const float* amp_w  = (const float*)d_in[21];
  const float* amp_b  = (const float*)d_in[22];
  const float* freq_w = (const float*)d_in[23];
  const float* freq_b = (const float*)d_in[24];
  const float* nm_w1  = (const float*)d_in[25];
  const float* nm_b1  = (const float*)d_in[26];
  const float* nm_w2  = (const float*)d_in[27];
  const float* nm_b2  = (const float*)d_in[28];
  const float* noise  = (const float*)d_in[29];

  float* ws = (float*)d_ws;
  float* buf0  = ws;                        // 262144 floats
  float* buf1  = ws + 262144;               // 262144
  float* hnorm = ws + 524288;               // 131072
  float* hh    = ws + 655360;               // 131072
  float* nbuf  = ws + 786432;               // 131072
  float* ncon  = ws + 917504;               // 2048
  double* P0g  = (double*)(ws + 919552);    // 4096*65 doubles (byte off %8==0)
  float4* segT = (float4*)(ws + 1452032);   // 4096*65 float4  (byte off %16==0)

  k_s0      <<<dim3(NB, 4), 256, 0, stream>>>(x, lin_w, lin_b, up_w0, up_b0, buf1);
  k_sN< 8>  <<<dim3(NB, 8), 256, 0, stream>>>(buf1, up_w1, up_b1, buf0);   // (B,128,16)
  k_sN<16>  <<<dim3(NB,16), 256, 0, stream>>>(buf0, up_w2, up_b2, buf1);   // (B,128,32)
  k_sN<32>  <<<dim3(NB,32), 256, 0, stream>>>(buf1, up_w3, up_b3, buf0);   // (B,128,64)
  k_s4n     <<<dim3(NB,16), 256, 0, stream>>>(buf0, fin_w, fin_b, hnorm);  // (B,64,64)
  k_mm12    <<<dim3(4, NB, 2), 256, 0, stream>>>(hnorm, hw1, hb1, hw2, hb2,
                                                 tw1, tb1, tw2, tb2, hh, nbuf);
  k_afp     <<<dim3(33, NB), 256, 0, stream>>>(hh, amp_w, amp_b, freq_w, freq_b,
                                               nbuf, nm_w1, nm_b1, nm_w2, nm_b2,
                                               noise, P0g, segT, ncon);
  k_harm    <<<dim3(64, NB), 256, 0, stream>>>(P0g, segT, ncon, (float*)d_out);
}

// Round 8
// 228.835 us; speedup vs baseline: 1.2594x; 1.2594x over previous
//
#include <hip/hip_runtime.h>
#include <math.h>

// DDSP-style Generator for MI355X.
// R1: split latency-bound k_heads -> 5 kernels. 407->246us.
// R3: split upconv monolith -> kmat/ups/conv. 246->228us.
// R5: launch-bound diagnosis (~8us/launch x 20).
// R6: fused to 8 kernels BUT k_sN recomputed the full-channel upsample per
//     g-block (32x duplication) -> k_sN<32>=99us, total 288us. REGRESSION.
// R8: upsample moved to the OUTPUT side: each conv block upsamples only its
//     own OCB channels (per-channel op, no duplication). Same 8 launches.
// All dot products accumulate in fp64 (freq path has ~5e4 amplification into tail phase).

static constexpr double PI_D     = 3.14159265358979323846;
static constexpr double LOWEST_D = 40.0 / 11025.0;
static constexpr double RT2O2    = 0.70710678118654752440;  // cos(pi/4)

#define NB    32
#define NFRM  64
#define NSMP  16384

// ---- k_A : lin -> (B,128,4) -> ups4->8 -> conv w0 + leaky -> ups8->16 -> u16 ----
__global__ __launch_bounds__(256) void k_A(const float* __restrict__ x,
    const float* __restrict__ lw, const float* __restrict__ lb,
    const float* __restrict__ w0, const float* __restrict__ b0,
    float* __restrict__ u16) {
  int b = blockIdx.x, g = blockIdx.y;          // g 0..3 -> 32 out channels
  int tid = threadIdx.x;
  __shared__ float  xs[128];
  __shared__ float  lin[512];
  __shared__ float  u8[1024];                  // 128 ch x 8
  __shared__ float  y[256];                    // 32 ch x 8 conv out
  __shared__ double Kt16[128];                 // [j<8][m<16]
  __shared__ double ctab16[16];
  if (tid < 128) xs[tid] = x[b*128 + tid];
  if (tid < 16)  ctab16[tid] = cos(PI_D*(double)tid/8.0);
  __syncthreads();
  {
    double a0 = 0.0, a1 = 0.0;
    for (int l = 0; l < 128; ++l) {
      double xv = (double)xs[l];
      a0 += xv * (double)lw[(size_t)l*512 + tid];
      a1 += xv * (double)lw[(size_t)l*512 + tid + 256];
    }
    lin[tid]     = (float)(a0 + (double)lb[tid]);
    lin[tid+256] = (float)(a1 + (double)lb[tid+256]);
  }
  if (tid < 128) {                             // Kt16 for 8->16 (reads ctab16 only)
    int j = tid >> 4, m = tid & 15;
    int dm = m - 2*j;
    double s = 1.0;
    #pragma unroll
    for (int k = 1; k <= 3; ++k) s += 2.0*ctab16[(k*dm) & 15];
    double cm2 = (m & 1) ? 0.0 : ((m & 2) ? -1.0 : 1.0);
    s += 2.0*cm2*((j & 1) ? -1.0 : 1.0);
    Kt16[j*16 + m] = s * 0.125;
  }
  __syncthreads();
  const double ct8[8] = {1.0, RT2O2, 0.0, -RT2O2, -1.0, -RT2O2, 0.0, RT2O2};
  #pragma unroll
  for (int rep = 0; rep < 4; ++rep) {          // ups4->8 (exact)
    int idx = tid + 256*rep;
    int c = idx >> 3, m = idx & 7;
    double cm2 = (m & 1) ? 0.0 : ((m & 2) ? -1.0 : 1.0);
    double a = 0.0;
    #pragma unroll
    for (int j = 0; j < 4; ++j) {
      double K = 0.25*(1.0 + 2.0*ct8[(m - 2*j) & 7] + 2.0*cm2*((j & 1) ? -1.0 : 1.0));
      a += K * (double)lin[c*4 + j];
    }
    u8[idx] = (float)a;
  }
  __syncthreads();
  int ol = tid >> 3, t = tid & 7;              // conv w0 @T=8
  int o = g*32 + ol;
  double a0 = 0.0, a1 = 0.0;
  const float* wp = w0 + (size_t)o*384;
  for (int c = 0; c < 128; ++c) {
    int base = c*8 + t;
    float xm = (t > 0) ? u8[base-1] : 0.f;
    float xc = u8[base];
    float xp = (t < 7) ? u8[base+1] : 0.f;
    a0 += (double)wp[c*3+0]*(double)xm + (double)wp[c*3+1]*(double)xc;
    a1 += (double)wp[c*3+2]*(double)xp;
  }
  float v = (float)(a0 + a1 + (double)b0[o]);
  y[tid] = (v > 0.f) ? v : 0.2f*v;
  __syncthreads();
  #pragma unroll
  for (int rep = 0; rep < 2; ++rep) {          // ups 8->16 of own channels
    int idx = tid + 256*rep;
    int c = idx >> 4, m = idx & 15;            // c 0..31
    double a = 0.0;
    #pragma unroll
    for (int j = 0; j < 8; ++j) a += Kt16[j*16 + m] * (double)y[c*8 + j];
    u16[((size_t)b*128 + g*32 + c)*16 + m] = (float)a;
  }
}

// ---- k_B : conv w1 @T=16 + leaky + ups16->32 -> u32 ----
__global__ __launch_bounds__(256) void k_B(const float* __restrict__ in,
    const float* __restrict__ w, const float* __restrict__ bias,
    float* __restrict__ u32) {
  int b = blockIdx.x, g = blockIdx.y;          // g 0..7 -> 16 out channels
  int tid = threadIdx.x;
  __shared__ float  u[128*16];
  __shared__ float  y[256];
  __shared__ double Kt[16*32];
  __shared__ double ctab[32];
  for (int i = tid; i < 2048; i += 256) u[i] = in[(size_t)b*2048 + i];
  if (tid < 32) ctab[tid] = cos(PI_D*(double)tid/16.0);
  __syncthreads();
  for (int i = tid; i < 512; i += 256) {
    int j = i >> 5, m = i & 31;
    int dm = m - 2*j;
    double s = 1.0;
    #pragma unroll
    for (int k = 1; k <= 7; ++k) s += 2.0*ctab[(k*dm) & 31];
    double cm2 = (m & 1) ? 0.0 : ((m & 2) ? -1.0 : 1.0);
    s += 2.0*cm2*((j & 1) ? -1.0 : 1.0);
    Kt[i] = s * (1.0/16.0);
  }
  int ol = tid >> 4, t = tid & 15;
  int o = g*16 + ol;
  double a0 = 0.0, a1 = 0.0;
  const float* wp = w + (size_t)o*384;
  for (int c = 0; c < 128; ++c) {
    int base = c*16 + t;
    float xm = (t > 0)  ? u[base-1] : 0.f;
    float xc = u[base];
    float xp = (t < 15) ? u[base+1] : 0.f;
    a0 += (double)wp[c*3+0]*(double)xm + (double)wp[c*3+1]*(double)xc;
    a1 += (double)wp[c*3+2]*(double)xp;
  }
  float v = (float)(a0 + a1 + (double)bias[o]);
  y[tid] = (v > 0.f) ? v : 0.2f*v;
  __syncthreads();
  #pragma unroll
  for (int rep = 0; rep < 2; ++rep) {
    int idx = tid + 256*rep;
    int c = idx >> 5, m = idx & 31;            // c 0..15
    double a = 0.0;
    #pragma unroll
    for (int j = 0; j < 16; ++j) a += Kt[j*32 + m] * (double)y[c*16 + j];
    u32[((size_t)b*128 + g*16 + c)*32 + m] = (float)a;
  }
}

// ---- k_C : conv w2 @T=32 + leaky + ups32->64 -> u64 ----
__global__ __launch_bounds__(256) void k_C(const float* __restrict__ in,
    const float* __restrict__ w, const float* __restrict__ bias,
    float* __restrict__ u64o) {
  int b = blockIdx.x, g = blockIdx.y;          // g 0..15 -> 8 out channels
  int tid = threadIdx.x;
  __shared__ float  u[128*32];                 // 16KB
  __shared__ float  y[256];
  __shared__ double Kt[32*64];                 // 16KB
  __shared__ double ctab[64];
  for (int i = tid; i < 4096; i += 256) u[i] = in[(size_t)b*4096 + i];
  if (tid < 64) ctab[tid] = cos(PI_D*(double)tid/32.0);
  __syncthreads();
  for (int i = tid; i < 2048; i += 256) {
    int j = i >> 6, m = i & 63;
    int dm = m - 2*j;
    double s = 1.0;
    #pragma unroll
    for (int k = 1; k <= 15; ++k) s += 2.0*ctab[(k*dm) & 63];
    double cm2 = (m & 1) ? 0.0 : ((m & 2) ? -1.0 : 1.0);
    s += 2.0*cm2*((j & 1) ? -1.0 : 1.0);
    Kt[i] = s * (1.0/32.0);
  }
  int ol = tid >> 5, t = tid & 31;
  int o = g*8 + ol;
  double a0 = 0.0, a1 = 0.0;
  const float* wp = w + (size_t)o*384;
  for (int c = 0; c < 128; ++c) {
    int base = c*32 + t;
    float xm = (t > 0)  ? u[base-1] : 0.f;
    float xc = u[base];
    float xp = (t < 31) ? u[base+1] : 0.f;
    a0 += (double)wp[c*3+0]*(double)xm + (double)wp[c*3+1]*(double)xc;
    a1 += (double)wp[c*3+2]*(double)xp;
  }
  float v = (float)(a0 + a1 + (double)bias[o]);
  y[tid] = (v > 0.f) ? v : 0.2f*v;
  __syncthreads();
  #pragma unroll
  for (int rep = 0; rep < 2; ++rep) {
    int idx = tid + 256*rep;
    int c = idx >> 6, m = idx & 63;            // c 0..7
    double a = 0.0;
    #pragma unroll 8
    for (int j = 0; j < 32; ++j) a += Kt[j*64 + m] * (double)y[c*32 + j];
    u64o[((size_t)b*128 + g*8 + c)*64 + m] = (float)a;
  }
}

// ---- k_D : conv w3 @T=64 + leaky (no ups) -> y4 ----
__global__ __launch_bounds__(256) void k_D(const float* __restrict__ in,
    const float* __restrict__ w, const float* __restrict__ bias,
    float* __restrict__ y4) {
  int b = blockIdx.x, g = blockIdx.y;          // g 0..31 -> 4 out channels
  int tid = threadIdx.x;
  __shared__ float u[128*64];                  // 32KB
  for (int i = tid; i < 8192; i += 256) u[i] = in[(size_t)b*8192 + i];
  __syncthreads();
  int ol = tid >> 6, t = tid & 63;
  int o = g*4 + ol;
  double a0 = 0.0, a1 = 0.0;
  const float* wp = w + (size_t)o*384;         // wave-uniform -> scalar loads
  for (int c = 0; c < 128; ++c) {
    int base = c*64 + t;
    float xm = (t > 0)  ? u[base-1] : 0.f;
    float xc = u[base];
    float xp = (t < 63) ? u[base+1] : 0.f;
    a0 += (double)wp[c*3+0]*(double)xm + (double)wp[c*3+1]*(double)xc;
    a1 += (double)wp[c*3+2]*(double)xp;
  }
  float v = (float)(a0 + a1 + (double)bias[o]);
  v = (v > 0.f) ? v : 0.2f*v;
  y4[((size_t)b*128 + o)*64 + t] = v;
}

// ---- k_s4n : final conv3 (128->64 ch, T=64, no act) + instance-norm (wave = channel) ----
__global__ __launch_bounds__(256) void k_s4n(const float* __restrict__ in,
    const float* __restrict__ fw, const float* __restrict__ fb,
    float* __restrict__ hnorm) {
  int b = blockIdx.x, g = blockIdx.y;          // g 0..15 -> 4 out channels
  int tid = threadIdx.x;
  __shared__ float uu[128*64];
  for (int i = tid; i < 128*64; i += 256) uu[i] = in[(size_t)b*8192 + i];
  __syncthreads();
  int ol = tid >> 6, t = tid & 63;
  int o = g*4 + ol;
  double a0 = 0.0, a1 = 0.0;
  const float* wp = fw + (size_t)o*384;        // wave-uniform -> scalar loads
  for (int c = 0; c < 128; ++c) {
    int base = c*64 + t;
    float xm = (t > 0)  ? uu[base-1] : 0.f;
    float xc = uu[base];
    float xp = (t < 63) ? uu[base+1] : 0.f;
    a0 += (double)wp[c*3+0]*(double)xm + (double)wp[c*3+1]*(double)xc;
    a1 += (double)wp[c*3+2]*(double)xp;
  }
  float vf = (float)(a0 + a1 + (double)fb[o]);
  double s = (double)vf;
  for (int off = 32; off > 0; off >>= 1) s += __shfl_down(s, off);
  double mean = __shfl(s, 0) * (1.0/64.0);
  double d = (double)vf - mean;
  double s2 = d*d;
  for (int off = 32; off > 0; off >>= 1) s2 += __shfl_down(s2, off);
  double var = __shfl(s2, 0) * (1.0/64.0);
  float sc = (float)(1.0 / sqrt(var + 1e-5));
  hnorm[((size_t)b*64 + o)*64 + t] = (float)d * sc;
}

// ---- k_mm12 : both 1x1-conv layers; block = (16 t-cols, b, chain z) ----
__global__ __launch_bounds__(256) void k_mm12(const float* __restrict__ hn,
    const float* __restrict__ hw1, const float* __restrict__ hb1,
    const float* __restrict__ hw2, const float* __restrict__ hb2,
    const float* __restrict__ tw1, const float* __restrict__ tb1,
    const float* __restrict__ tw2, const float* __restrict__ tb2,
    float* __restrict__ hh, float* __restrict__ nbuf) {
  int tq = blockIdx.x, b = blockIdx.y, z = blockIdx.z;
  int tid = threadIdx.x;
  const float* W1 = z ? tw1 : hw1; const float* B1 = z ? tb1 : hb1;
  const float* W2 = z ? tw2 : hw2; const float* B2 = z ? tb2 : hb2;
  __shared__ float h0[64*16];
  __shared__ float t1[64*16];
  for (int i = tid; i < 1024; i += 256) {
    int c = i >> 4, tt = i & 15;
    h0[i] = hn[((size_t)b*64 + c)*64 + tq*16 + tt];
  }
  __syncthreads();
  int t = tid & 15, ob = tid >> 4;             // ob 0..15, 4 o's per thread
  #pragma unroll
  for (int k = 0; k < 4; ++k) {
    int o = ob + 16*k;
    double a0 = 0.0, a1 = 0.0;
    const float* wp = W1 + o*64;
    for (int c = 0; c < 64; c += 2) {
      a0 += (double)wp[c]  *(double)h0[c*16 + t];
      a1 += (double)wp[c+1]*(double)h0[(c+1)*16 + t];
    }
    float v = (float)(a0 + a1 + (double)B1[o]);
    v = (v > 0.f) ? v : 0.2f*v;
    t1[o*16 + t] = v;
  }
  __syncthreads();
  float* out = z ? nbuf : hh;
  #pragma unroll
  for (int k = 0; k < 4; ++k) {
    int o = ob + 16*k;
    double a0 = 0.0, a1 = 0.0;
    const float* wp = W2 + o*64;
    for (int c = 0; c < 64; c += 2) {
      a0 += (double)wp[c]  *(double)t1[c*16 + t];
      a1 += (double)wp[c+1]*(double)t1[(c+1)*16 + t];
    }
    out[((size_t)b*64 + o)*64 + tq*16 + t] = (float)(a0 + a1 + (double)B2[o]);
  }
}

// ---- k_afp : amp/freq heads + shfl-scan prefix (g<32); dc+ncon (g==32) ----
// P0[j] = 64*(F_{j-1}+F_{j-2}) with F = inclusive lane-scan of f (fp64), F_{-1}=0.
// Layout: P0g/segT rows [b*128+osc]*65 + j  -> scan-lane writes are coalesced.
__global__ __launch_bounds__(256) void k_afp(const float* __restrict__ hh,
    const float* __restrict__ amp_w, const float* __restrict__ amp_b,
    const float* __restrict__ freq_w, const float* __restrict__ freq_b,
    const float* __restrict__ nbuf,
    const float* __restrict__ nm_w1, const float* __restrict__ nm_b1,
    const float* __restrict__ nm_w2, const float* __restrict__ nm_b2,
    const float* __restrict__ noise,
    double* __restrict__ P0g, float4* __restrict__ segT,
    float* __restrict__ ncon) {
  int g = blockIdx.x, b = blockIdx.y;
  int tid = threadIdx.x;
  if (g < 32) {
    int ow = tid >> 6;                         // wave -> oscillator
    int o = g*4 + ow;
    int lane = tid & 63;                       // frame j
    const float* X  = hh + (size_t)b*4096 + lane;
    const float* wa = amp_w + o*64;
    const float* wf = freq_w + o*64;
    double za = (double)amp_b[o], zf = (double)freq_b[o];
    for (int c = 0; c < 64; ++c) {
      double hv = (double)X[(size_t)c*64];
      za += (double)wa[c]*hv;
      zf += (double)wf[c]*hv;
    }
    float a = fabsf((float)za);
    double sg = 1.0/(1.0 + exp(-zf));
    float f = (float)(LOWEST_D + sg*sg*(1.0 - LOWEST_D));
    double F = (double)f;                      // inclusive scan over 64 lanes
    #pragma unroll
    for (int off = 1; off < 64; off <<= 1) {
      double n = __shfl_up(F, off);
      if (lane >= off) F += n;
    }
    double Fm1 = __shfl_up(F, 1); if (lane < 1) Fm1 = 0.0;
    double Fm2 = __shfl_up(F, 2); if (lane < 2) Fm2 = 0.0;
    float fm1 = __shfl_up(f, 1);
    float am1 = __shfl_up(a, 1);
    size_t row = ((size_t)b*128 + o)*65;
    P0g[row + lane] = (lane == 0) ? 0.0 : 64.0*(Fm1 + Fm2);
    segT[row + lane] = (lane == 0) ? make_float4(f, 0.f, a, 0.f)
                                   : make_float4(fm1, f - fm1, am1, a - am1);
    if (lane == 63) {
      P0g[row + 64]  = 64.0*(F + Fm1);
      segT[row + 64] = make_float4(f, 0.f, a, 0.f);
    }
  } else {
    __shared__ double veff[64];
    __shared__ double dcs[64];
    if (tid < 64) {                            // veff[m] = sum_c nm_w2[0,c]*nm_w1[c,m]
      double a = 0.0;
      for (int c = 0; c < 128; ++c) a += (double)nm_w2[c]*(double)nm_w1[c*64 + tid];
      veff[tid] = a;
    }
    double beff = (double)nm_b2[0];
    for (int c = 0; c < 128; ++c) beff += (double)nm_w2[c]*(double)nm_b1[c];
    int wv = tid >> 6, lane = tid & 63;
    for (int k = 0; k < 16; ++k) {             // dc of 16 frames per wave
      int fr = wv*16 + k;
      const float* p = noise + ((size_t)b*64 + fr)*512;
      double s = 0.0;
      for (int i = lane; i < 512; i += 64) s += (double)p[i];
      for (int off = 32; off > 0; off >>= 1) s += __shfl_down(s, off);
      if (lane == 0) dcs[fr] = s;
    }
    __syncthreads();
    if (tid < 64) {
      int fr = tid;
      double s0 = beff;
      for (int m = 0; m < 64; ++m) s0 += veff[m]*(double)nbuf[((size_t)b*64 + m)*64 + fr];
      ncon[b*64 + fr] = (float)(dcs[fr]*s0*(1.0/512.0));
    }
  }
}

// ---- k_harm : block = (q,b): 256 samples x 128 oscillators ----
// rev(s) = P0 + 0.5*[(r+1)*f_lo + ((r+1)*w0 + r(r+1)/512)*df], fract -> v_sin_f32.
__global__ __launch_bounds__(256) void k_harm(const double* __restrict__ P0g,
                                              const float4* __restrict__ segT,
                                              const float* __restrict__ nc,
                                              float* __restrict__ outp) {
  int q = blockIdx.x;                          // 0..63
  int b = blockIdx.y;
  int tid = threadIdx.x;
  __shared__ double P0s[256];                  // [half][osc]
  __shared__ float4 segs[256];
  int half = tid >> 7;
  int osc  = tid & 127;
  {
    size_t row = ((size_t)b*128 + osc)*65 + (q + half);
    P0s[tid]  = P0g[row];
    segs[tid] = segT[row];
  }
  __syncthreads();

  int j = q + half;
  int s = q*256 + tid;
  int r = (j == 0) ? s : (s - (256*j - 128));
  float w0 = (j == 0 || j == 64) ? 0.f : (1.f/512.f);
  double rp = (double)(r + 1);
  double c1 = rp * 0.5;
  double c2 = (rp*(double)w0 + (double)r*rp*(1.0/512.0)) * 0.5;
  float wr = w0 + (float)r*(1.f/256.f);

  const double* P0p = P0s + half*128;
  const float4* sp  = segs + half*128;
  float acc = 0.f;
  #pragma unroll 4
  for (int o = 0; o < 128; ++o) {
    float4 sg = sp[o];                         // {f_lo, df, a_lo, da}
    double rev = P0p[o] + c1*(double)sg.x + c2*(double)sg.y;
    rev -= floor(rev);
    float sv = __builtin_amdgcn_sinf((float)rev);   // sin(2*pi*x)
    float am = sg.z + sg.w*wr;
    acc = fmaf(sv, am, acc);
  }
  float ns = nc[b*NFRM + q] + ((q > 0) ? nc[b*NFRM + q - 1] : 0.f);
  outp[(size_t)b*NSMP + s] = acc + ns;
}

// ---------------------------------------------------------------------------
extern "C" void kernel_launch(void* const* d_in, const int* in_sizes, int n_in,
                              void* d_out, int out_size, void* d_ws, size_t ws_size,
                              hipStream_t stream) {
  (void)in_sizes; (void)n_in; (void)out_size; (void)ws_size;
  const float* x      = (const float*)d_in[0];
  const float* lin_w  = (const float*)d_in[1];
  const float* lin_b  = (const float*)d_in[2];
  const float* up_w0  = (const float*)d_in[3];
  const float* up_b0  = (const float*)d_in[4];
  const float* up_w1  = (const float*)d_in[5];
  const float* up_b1  = (const float*)d_in[6];
  const float* up_w2  = (const float*)d_in[7];
  const float* up_b2  = (const float*)d_in[8];
  const float* up_w3  = (const float*)d_in[9];
  const float* up_b3  = (const float*)d_in[10];
  const float* fin_w  = (const float*)d_in[11];
  const float* fin_b  = (const float*)d_in[12];
  const float* hw1    = (const float*)d_in[13];
  const float* hb1    = (const float*)d_in[14];
  const float* hw2    = (const float*)d_in[15];
  const float* hb2    = (const float*)d_in[16];
  const float* tw1    = (const float*)d_in[17];
  const float* tb1    = (const float*)d_in[18];
  const float* tw2    = (const float*)d_in[19];
  const float* tb2    = (const float*)d_in[20];
  const float* amp_w  = (const float*)d_in[21];
  const float* amp_b  = (const float*)d_in[22];
  const float* freq_w = (const float*)d_in[23];
  const float* freq_b = (const float*)d_in[24];
  const float* nm_w1  = (const float*)d_in[25];
  const float* nm_b1  = (const float*)d_in[26];
  const float* nm_w2  = (const float*)d_in[27];
  const float* nm_b2  = (const float*)d_in[28];
  const float* noise  = (const float*)d_in[29];

  float* ws = (float*)d_ws;
  float* buf0  = ws;                        // 262144 floats
  float* buf1  = ws + 262144;               // 262144
  float* hnorm = ws + 524288;               // 131072
  float* hh    = ws + 655360;               // 131072
  float* nbuf  = ws + 786432;               // 131072
  float* ncon  = ws + 917504;               // 2048
  double* P0g  = (double*)(ws + 919552);    // 4096*65 doubles (byte off %8==0)
  float4* segT = (float4*)(ws + 1452032);   // 4096*65 float4  (byte off %16==0)

  // upconv chain buffers (ping-pong, regions dead before reuse):
  float* u16 = buf1;                        // (B,128,16) = 65536
  float* u32 = buf0;                        // (B,128,32) = 131072
  float* u64b = buf1;                       // (B,128,64) = 262144 (u16 dead)
  float* y4  = buf0;                        // (B,128,64) = 262144 (u32 dead)

  k_A   <<<dim3(NB, 4), 256, 0, stream>>>(x, lin_w, lin_b, up_w0, up_b0, u16);
  k_B   <<<dim3(NB, 8), 256, 0, stream>>>(u16, up_w1, up_b1, u32);
  k_C   <<<dim3(NB,16), 256, 0, stream>>>(u32, up_w2, up_b2, u64b);
  k_D   <<<dim3(NB,32), 256, 0, stream>>>(u64b, up_w3, up_b3, y4);
  k_s4n <<<dim3(NB,16), 256, 0, stream>>>(y4, fin_w, fin_b, hnorm);
  k_mm12<<<dim3(4, NB, 2), 256, 0, stream>>>(hnorm, hw1, hb1, hw2, hb2,
                                             tw1, tb1, tw2, tb2, hh, nbuf);
  k_afp <<<dim3(33, NB), 256, 0, stream>>>(hh, amp_w, amp_b, freq_w, freq_b,
                                           nbuf, nm_w1, nm_b1, nm_w2, nm_b2,
                                           noise, P0g, segT, ncon);
  k_harm<<<dim3(64, NB), 256, 0, stream>>>(P0g, segT, ncon, (float*)d_out);
}

// Round 10
// 186.808 us; speedup vs baseline: 1.5428x; 1.2250x over previous
//
#include <hip/hip_runtime.h>
#include <math.h>

// DDSP-style Generator for MI355X.
// R1: split latency-bound k_heads -> 5 kernels. 407->246us.
// R3: split upconv monolith -> kmat/ups/conv. 246->228us.
// R6: 8-kernel fusion, but upsample duplicated 32x -> 288us. REGRESSION.
// R8: output-side upsample fix -> 228us; k_afp=60us: noise-DC tail (32 blocks
//     serially chewing 4MB of HBM-cold noise at 74 GB/s).
// R9: noise-DC rides k_A's launch as 512 extra blocks (one wave per frame,
//     2048-way parallel); k_afp g==32 keeps only veff/beff/ncon. 3-chain ILP
//     in k_D/k_s4n.
// R10: resubmit (infra failure, no data).
// All dot products accumulate in fp64 (freq path has ~5e4 amplification into tail phase).

static constexpr double PI_D     = 3.14159265358979323846;
static constexpr double LOWEST_D = 40.0 / 11025.0;
static constexpr double RT2O2    = 0.70710678118654752440;  // cos(pi/4)

#define NB    32
#define NFRM  64
#define NSMP  16384

// ---- k_A : g<4: lin -> ups4->8 -> conv w0 + leaky -> ups8->16.  g>=4: noise-DC ----
__global__ __launch_bounds__(256) void k_A(const float* __restrict__ x,
    const float* __restrict__ lw, const float* __restrict__ lb,
    const float* __restrict__ w0, const float* __restrict__ b0,
    float* __restrict__ u16,
    const float* __restrict__ noise, float* __restrict__ dcw) {
  int b = blockIdx.x, g = blockIdx.y;
  int tid = threadIdx.x;
  if (g >= 4) {                                // DC of noise windows: 1 wave = 1 frame
    int gp = g - 4;                            // 0..15
    int wv = tid >> 6, lane = tid & 63;
    int fr = gp*4 + wv;                        // 0..63
    const float* p = noise + ((size_t)b*NFRM + fr)*512;
    double s = 0.0;
    #pragma unroll
    for (int i = 0; i < 8; ++i) s += (double)p[lane + i*64];
    for (int off = 32; off > 0; off >>= 1) s += __shfl_down(s, off);
    if (lane == 0) dcw[b*NFRM + fr] = (float)s;
    return;
  }
  __shared__ float  xs[128];
  __shared__ float  lin[512];
  __shared__ float  u8[1024];                  // 128 ch x 8
  __shared__ float  y[256];                    // 32 ch x 8 conv out
  __shared__ double Kt16[128];                 // [j<8][m<16]
  __shared__ double ctab16[16];
  if (tid < 128) xs[tid] = x[b*128 + tid];
  if (tid < 16)  ctab16[tid] = cos(PI_D*(double)tid/8.0);
  __syncthreads();
  {
    double a0 = 0.0, a1 = 0.0;
    for (int l = 0; l < 128; ++l) {
      double xv = (double)xs[l];
      a0 += xv * (double)lw[(size_t)l*512 + tid];
      a1 += xv * (double)lw[(size_t)l*512 + tid + 256];
    }
    lin[tid]     = (float)(a0 + (double)lb[tid]);
    lin[tid+256] = (float)(a1 + (double)lb[tid+256]);
  }
  if (tid < 128) {                             // Kt16 for 8->16 (reads ctab16 only)
    int j = tid >> 4, m = tid & 15;
    int dm = m - 2*j;
    double s = 1.0;
    #pragma unroll
    for (int k = 1; k <= 3; ++k) s += 2.0*ctab16[(k*dm) & 15];
    double cm2 = (m & 1) ? 0.0 : ((m & 2) ? -1.0 : 1.0);
    s += 2.0*cm2*((j & 1) ? -1.0 : 1.0);
    Kt16[j*16 + m] = s * 0.125;
  }
  __syncthreads();
  const double ct8[8] = {1.0, RT2O2, 0.0, -RT2O2, -1.0, -RT2O2, 0.0, RT2O2};
  #pragma unroll
  for (int rep = 0; rep < 4; ++rep) {          // ups4->8 (exact)
    int idx = tid + 256*rep;
    int c = idx >> 3, m = idx & 7;
    double cm2 = (m & 1) ? 0.0 : ((m & 2) ? -1.0 : 1.0);
    double a = 0.0;
    #pragma unroll
    for (int j = 0; j < 4; ++j) {
      double K = 0.25*(1.0 + 2.0*ct8[(m - 2*j) & 7] + 2.0*cm2*((j & 1) ? -1.0 : 1.0));
      a += K * (double)lin[c*4 + j];
    }
    u8[idx] = (float)a;
  }
  __syncthreads();
  int ol = tid >> 3, t = tid & 7;              // conv w0 @T=8
  int o = g*32 + ol;
  double a0 = 0.0, a1 = 0.0;
  const float* wp = w0 + (size_t)o*384;
  for (int c = 0; c < 128; ++c) {
    int base = c*8 + t;
    float xm = (t > 0) ? u8[base-1] : 0.f;
    float xc = u8[base];
    float xp = (t < 7) ? u8[base+1] : 0.f;
    a0 += (double)wp[c*3+0]*(double)xm + (double)wp[c*3+1]*(double)xc;
    a1 += (double)wp[c*3+2]*(double)xp;
  }
  float v = (float)(a0 + a1 + (double)b0[o]);
  y[tid] = (v > 0.f) ? v : 0.2f*v;
  __syncthreads();
  #pragma unroll
  for (int rep = 0; rep < 2; ++rep) {          // ups 8->16 of own channels
    int idx = tid + 256*rep;
    int c = idx >> 4, m = idx & 15;            // c 0..31
    double a = 0.0;
    #pragma unroll
    for (int j = 0; j < 8; ++j) a += Kt16[j*16 + m] * (double)y[c*8 + j];
    u16[((size_t)b*128 + g*32 + c)*16 + m] = (float)a;
  }
}

// ---- k_B : conv w1 @T=16 + leaky + ups16->32 -> u32 ----
__global__ __launch_bounds__(256) void k_B(const float* __restrict__ in,
    const float* __restrict__ w, const float* __restrict__ bias,
    float* __restrict__ u32) {
  int b = blockIdx.x, g = blockIdx.y;          // g 0..7 -> 16 out channels
  int tid = threadIdx.x;
  __shared__ float  u[128*16];
  __shared__ float  y[256];
  __shared__ double Kt[16*32];
  __shared__ double ctab[32];
  for (int i = tid; i < 2048; i += 256) u[i] = in[(size_t)b*2048 + i];
  if (tid < 32) ctab[tid] = cos(PI_D*(double)tid/16.0);
  __syncthreads();
  for (int i = tid; i < 512; i += 256) {
    int j = i >> 5, m = i & 31;
    int dm = m - 2*j;
    double s = 1.0;
    #pragma unroll
    for (int k = 1; k <= 7; ++k) s += 2.0*ctab[(k*dm) & 31];
    double cm2 = (m & 1) ? 0.0 : ((m & 2) ? -1.0 : 1.0);
    s += 2.0*cm2*((j & 1) ? -1.0 : 1.0);
    Kt[i] = s * (1.0/16.0);
  }
  int ol = tid >> 4, t = tid & 15;
  int o = g*16 + ol;
  double a0 = 0.0, a1 = 0.0;
  const float* wp = w + (size_t)o*384;
  for (int c = 0; c < 128; ++c) {
    int base = c*16 + t;
    float xm = (t > 0)  ? u[base-1] : 0.f;
    float xc = u[base];
    float xp = (t < 15) ? u[base+1] : 0.f;
    a0 += (double)wp[c*3+0]*(double)xm + (double)wp[c*3+1]*(double)xc;
    a1 += (double)wp[c*3+2]*(double)xp;
  }
  float v = (float)(a0 + a1 + (double)bias[o]);
  y[tid] = (v > 0.f) ? v : 0.2f*v;
  __syncthreads();
  #pragma unroll
  for (int rep = 0; rep < 2; ++rep) {
    int idx = tid + 256*rep;
    int c = idx >> 5, m = idx & 31;            // c 0..15
    double a = 0.0;
    #pragma unroll
    for (int j = 0; j < 16; ++j) a += Kt[j*32 + m] * (double)y[c*16 + j];
    u32[((size_t)b*128 + g*16 + c)*32 + m] = (float)a;
  }
}

// ---- k_C : conv w2 @T=32 + leaky + ups32->64 -> u64 ----
__global__ __launch_bounds__(256) void k_C(const float* __restrict__ in,
    const float* __restrict__ w, const float* __restrict__ bias,
    float* __restrict__ u64o) {
  int b = blockIdx.x, g = blockIdx.y;          // g 0..15 -> 8 out channels
  int tid = threadIdx.x;
  __shared__ float  u[128*32];                 // 16KB
  __shared__ float  y[256];
  __shared__ double Kt[32*64];                 // 16KB
  __shared__ double ctab[64];
  for (int i = tid; i < 4096; i += 256) u[i] = in[(size_t)b*4096 + i];
  if (tid < 64) ctab[tid] = cos(PI_D*(double)tid/32.0);
  __syncthreads();
  for (int i = tid; i < 2048; i += 256) {
    int j = i >> 6, m = i & 63;
    int dm = m - 2*j;
    double s = 1.0;
    #pragma unroll
    for (int k = 1; k <= 15; ++k) s += 2.0*ctab[(k*dm) & 63];
    double cm2 = (m & 1) ? 0.0 : ((m & 2) ? -1.0 : 1.0);
    s += 2.0*cm2*((j & 1) ? -1.0 : 1.0);
    Kt[i] = s * (1.0/32.0);
  }
  int ol = tid >> 5, t = tid & 31;
  int o = g*8 + ol;
  double a0 = 0.0, a1 = 0.0;
  const float* wp = w + (size_t)o*384;
  for (int c = 0; c < 128; ++c) {
    int base = c*32 + t;
    float xm = (t > 0)  ? u[base-1] : 0.f;
    float xc = u[base];
    float xp = (t < 31) ? u[base+1] : 0.f;
    a0 += (double)wp[c*3+0]*(double)xm + (double)wp[c*3+1]*(double)xc;
    a1 += (double)wp[c*3+2]*(double)xp;
  }
  float v = (float)(a0 + a1 + (double)bias[o]);
  y[tid] = (v > 0.f) ? v : 0.2f*v;
  __syncthreads();
  #pragma unroll
  for (int rep = 0; rep < 2; ++rep) {
    int idx = tid + 256*rep;
    int c = idx >> 6, m = idx & 63;            // c 0..7
    double a = 0.0;
    #pragma unroll 8
    for (int j = 0; j < 32; ++j) a += Kt[j*64 + m] * (double)y[c*32 + j];
    u64o[((size_t)b*128 + g*8 + c)*64 + m] = (float)a;
  }
}

// ---- k_D : conv w3 @T=64 + leaky (no ups) -> y4 ----
__global__ __launch_bounds__(256) void k_D(const float* __restrict__ in,
    const float* __restrict__ w, const float* __restrict__ bias,
    float* __restrict__ y4) {
  int b = blockIdx.x, g = blockIdx.y;          // g 0..31 -> 4 out channels
  int tid = threadIdx.x;
  __shared__ float u[128*64];                  // 32KB
  for (int i = tid; i < 8192; i += 256) u[i] = in[(size_t)b*8192 + i];
  __syncthreads();
  int ol = tid >> 6, t = tid & 63;
  int o = g*4 + ol;
  double a0 = 0.0, a1 = 0.0, a2 = 0.0;         // 3 independent fp64 chains
  const float* wp = w + (size_t)o*384;         // wave-uniform -> scalar loads
  for (int c = 0; c < 128; ++c) {
    int base = c*64 + t;
    float xm = (t > 0)  ? u[base-1] : 0.f;
    float xc = u[base];
    float xp = (t < 63) ? u[base+1] : 0.f;
    a0 += (double)wp[c*3+0]*(double)xm;
    a1 += (double)wp[c*3+1]*(double)xc;
    a2 += (double)wp[c*3+2]*(double)xp;
  }
  float v = (float)(a0 + a1 + a2 + (double)bias[o]);
  v = (v > 0.f) ? v : 0.2f*v;
  y4[((size_t)b*128 + o)*64 + t] = v;
}

// ---- k_s4n : final conv3 (128->64 ch, T=64, no act) + instance-norm (wave = channel) ----
__global__ __launch_bounds__(256) void k_s4n(const float* __restrict__ in,
    const float* __restrict__ fw, const float* __restrict__ fb,
    float* __restrict__ hnorm) {
  int b = blockIdx.x, g = blockIdx.y;          // g 0..15 -> 4 out channels
  int tid = threadIdx.x;
  __shared__ float uu[128*64];
  for (int i = tid; i < 128*64; i += 256) uu[i] = in[(size_t)b*8192 + i];
  __syncthreads();
  int ol = tid >> 6, t = tid & 63;
  int o = g*4 + ol;
  double a0 = 0.0, a1 = 0.0, a2 = 0.0;
  const float* wp = fw + (size_t)o*384;        // wave-uniform -> scalar loads
  for (int c = 0; c < 128; ++c) {
    int base = c*64 + t;
    float xm = (t > 0)  ? uu[base-1] : 0.f;
    float xc = uu[base];
    float xp = (t < 63) ? uu[base+1] : 0.f;
    a0 += (double)wp[c*3+0]*(double)xm;
    a1 += (double)wp[c*3+1]*(double)xc;
    a2 += (double)wp[c*3+2]*(double)xp;
  }
  float vf = (float)(a0 + a1 + a2 + (double)fb[o]);
  double s = (double)vf;
  for (int off = 32; off > 0; off >>= 1) s += __shfl_down(s, off);
  double mean = __shfl(s, 0) * (1.0/64.0);
  double d = (double)vf - mean;
  double s2 = d*d;
  for (int off = 32; off > 0; off >>= 1) s2 += __shfl_down(s2, off);
  double var = __shfl(s2, 0) * (1.0/64.0);
  float sc = (float)(1.0 / sqrt(var + 1e-5));
  hnorm[((size_t)b*64 + o)*64 + t] = (float)d * sc;
}

// ---- k_mm12 : both 1x1-conv layers; block = (16 t-cols, b, chain z) ----
__global__ __launch_bounds__(256) void k_mm12(const float* __restrict__ hn,
    const float* __restrict__ hw1, const float* __restrict__ hb1,
    const float* __restrict__ hw2, const float* __restrict__ hb2,
    const float* __restrict__ tw1, const float* __restrict__ tb1,
    const float* __restrict__ tw2, const float* __restrict__ tb2,
    float* __restrict__ hh, float* __restrict__ nbuf) {
  int tq = blockIdx.x, b = blockIdx.y, z = blockIdx.z;
  int tid = threadIdx.x;
  const float* W1 = z ? tw1 : hw1; const float* B1 = z ? tb1 : hb1;
  const float* W2 = z ? tw2 : hw2; const float* B2 = z ? tb2 : hb2;
  __shared__ float h0[64*16];
  __shared__ float t1[64*16];
  for (int i = tid; i < 1024; i += 256) {
    int c = i >> 4, tt = i & 15;
    h0[i] = hn[((size_t)b*64 + c)*64 + tq*16 + tt];
  }
  __syncthreads();
  int t = tid & 15, ob = tid >> 4;             // ob 0..15, 4 o's per thread
  #pragma unroll
  for (int k = 0; k < 4; ++k) {
    int o = ob + 16*k;
    double a0 = 0.0, a1 = 0.0;
    const float* wp = W1 + o*64;
    for (int c = 0; c < 64; c += 2) {
      a0 += (double)wp[c]  *(double)h0[c*16 + t];
      a1 += (double)wp[c+1]*(double)h0[(c+1)*16 + t];
    }
    float v = (float)(a0 + a1 + (double)B1[o]);
    v = (v > 0.f) ? v : 0.2f*v;
    t1[o*16 + t] = v;
  }
  __syncthreads();
  float* out = z ? nbuf : hh;
  #pragma unroll
  for (int k = 0; k < 4; ++k) {
    int o = ob + 16*k;
    double a0 = 0.0, a1 = 0.0;
    const float* wp = W2 + o*64;
    for (int c = 0; c < 64; c += 2) {
      a0 += (double)wp[c]  *(double)t1[c*16 + t];
      a1 += (double)wp[c+1]*(double)t1[(c+1)*16 + t];
    }
    out[((size_t)b*64 + o)*64 + tq*16 + t] = (float)(a0 + a1 + (double)B2[o]);
  }
}

// ---- k_afp : amp/freq heads + shfl-scan prefix (g<32); veff/ncon (g==32) ----
// P0[j] = 64*(F_{j-1}+F_{j-2}) with F = inclusive lane-scan of f (fp64), F_{-1}=0.
// Layout: P0g/segT rows [b*128+osc]*65 + j  -> scan-lane writes are coalesced.
__global__ __launch_bounds__(256) void k_afp(const float* __restrict__ hh,
    const float* __restrict__ amp_w, const float* __restrict__ amp_b,
    const float* __restrict__ freq_w, const float* __restrict__ freq_b,
    const float* __restrict__ nbuf,
    const float* __restrict__ nm_w1, const float* __restrict__ nm_b1,
    const float* __restrict__ nm_w2, const float* __restrict__ nm_b2,
    const float* __restrict__ dcw,
    double* __restrict__ P0g, float4* __restrict__ segT,
    float* __restrict__ ncon) {
  int g = blockIdx.x, b = blockIdx.y;
  int tid = threadIdx.x;
  if (g < 32) {
    int ow = tid >> 6;                         // wave -> oscillator
    int o = g*4 + ow;
    int lane = tid & 63;                       // frame j
    const float* X  = hh + (size_t)b*4096 + lane;
    const float* wa = amp_w + o*64;
    const float* wf = freq_w + o*64;
    double za = (double)amp_b[o], zf = (double)freq_b[o];
    for (int c = 0; c < 64; ++c) {
      double hv = (double)X[(size_t)c*64];
      za += (double)wa[c]*hv;
      zf += (double)wf[c]*hv;
    }
    float a = fabsf((float)za);
    double sg = 1.0/(1.0 + exp(-zf));
    float f = (float)(LOWEST_D + sg*sg*(1.0 - LOWEST_D));
    double F = (double)f;                      // inclusive scan over 64 lanes
    #pragma unroll
    for (int off = 1; off < 64; off <<= 1) {
      double n = __shfl_up(F, off);
      if (lane >= off) F += n;
    }
    double Fm1 = __shfl_up(F, 1); if (lane < 1) Fm1 = 0.0;
    double Fm2 = __shfl_up(F, 2); if (lane < 2) Fm2 = 0.0;
    float fm1 = __shfl_up(f, 1);
    float am1 = __shfl_up(a, 1);
    size_t row = ((size_t)b*128 + o)*65;
    P0g[row + lane] = (lane == 0) ? 0.0 : 64.0*(Fm1 + Fm2);
    segT[row + lane] = (lane == 0) ? make_float4(f, 0.f, a, 0.f)
                                   : make_float4(fm1, f - fm1, am1, a - am1);
    if (lane == 63) {
      P0g[row + 64]  = 64.0*(F + Fm1);
      segT[row + 64] = make_float4(f, 0.f, a, 0.f);
    }
  } else {
    __shared__ double veff[64];
    if (tid < 64) {                            // veff[m] = sum_c nm_w2[0,c]*nm_w1[c,m]
      double a = 0.0;
      for (int c = 0; c < 128; ++c) a += (double)nm_w2[c]*(double)nm_w1[c*64 + tid];
      veff[tid] = a;
    }
    __syncthreads();
    if (tid < 64) {
      double beff = (double)nm_b2[0];
      for (int c = 0; c < 128; ++c) beff += (double)nm_w2[c]*(double)nm_b1[c];
      int fr = tid;
      double s0 = beff;
      for (int m = 0; m < 64; ++m) s0 += veff[m]*(double)nbuf[((size_t)b*64 + m)*64 + fr];
      ncon[b*NFRM + fr] = (float)((double)dcw[b*NFRM + fr]*s0*(1.0/512.0));
    }
  }
}

// ---- k_harm : block = (q,b): 256 samples x 128 oscillators ----
// rev(s) = P0 + 0.5*[(r+1)*f_lo + ((r+1)*w0 + r(r+1)/512)*df], fract -> v_sin_f32.
__global__ __launch_bounds__(256) void k_harm(const double* __restrict__ P0g,
                                              const float4* __restrict__ segT,
                                              const float* __restrict__ nc,
                                              float* __restrict__ outp) {
  int q = blockIdx.x;                          // 0..63
  int b = blockIdx.y;
  int tid = threadIdx.x;
  __shared__ double P0s[256];                  // [half][osc]
  __shared__ float4 segs[256];
  int half = tid >> 7;
  int osc  = tid & 127;
  {
    size_t row = ((size_t)b*128 + osc)*65 + (q + half);
    P0s[tid]  = P0g[row];
    segs[tid] = segT[row];
  }
  __syncthreads();

  int j = q + half;
  int s = q*256 + tid;
  int r = (j == 0) ? s : (s - (256*j - 128));
  float w0 = (j == 0 || j == 64) ? 0.f : (1.f/512.f);
  double rp = (double)(r + 1);
  double c1 = rp * 0.5;
  double c2 = (rp*(double)w0 + (double)r*rp*(1.0/512.0)) * 0.5;
  float wr = w0 + (float)r*(1.f/256.f);

  const double* P0p = P0s + half*128;
  const float4* sp  = segs + half*128;
  float acc = 0.f;
  #pragma unroll 4
  for (int o = 0; o < 128; ++o) {
    float4 sg = sp[o];                         // {f_lo, df, a_lo, da}
    double rev = P0p[o] + c1*(double)sg.x + c2*(double)sg.y;
    rev -= floor(rev);
    float sv = __builtin_amdgcn_sinf((float)rev);   // sin(2*pi*x)
    float am = sg.z + sg.w*wr;
    acc = fmaf(sv, am, acc);
  }
  float ns = nc[b*NFRM + q] + ((q > 0) ? nc[b*NFRM + q - 1] : 0.f);
  outp[(size_t)b*NSMP + s] = acc + ns;
}

// ---------------------------------------------------------------------------
extern "C" void kernel_launch(void* const* d_in, const int* in_sizes, int n_in,
                              void* d_out, int out_size, void* d_ws, size_t ws_size,
                              hipStream_t stream) {
  (void)in_sizes; (void)n_in; (void)out_size; (void)ws_size;
  const float* x      = (const float*)d_in[0];
  const float* lin_w  = (const float*)d_in[1];
  const float* lin_b  = (const float*)d_in[2];
  const float* up_w0  = (const float*)d_in[3];
  const float* up_b0  = (const float*)d_in[4];
  const float* up_w1  = (const float*)d_in[5];
  const float* up_b1  = (const float*)d_in[6];
  const float* up_w2  = (const float*)d_in[7];
  const float* up_b2  = (const float*)d_in[8];
  const float* up_w3  = (const float*)d_in[9];
  const float* up_b3  = (const float*)d_in[10];
  const float* fin_w  = (const float*)d_in[11];
  const float* fin_b  = (const float*)d_in[12];
  const float* hw1    = (const float*)d_in[13];
  const float* hb1    = (const float*)d_in[14];
  const float* hw2    = (const float*)d_in[15];
  const float* hb2    = (const float*)d_in[16];
  const float* tw1    = (const float*)d_in[17];
  const float* tb1    = (const float*)d_in[18];
  const float* tw2    = (const float*)d_in[19];
  const float* tb2    = (const float*)d_in[20];
  const float* amp_w  = (const float*)d_in[21];
  const float* amp_b  = (const float*)d_in[22];
  const float* freq_w = (const float*)d_in[23];
  const float* freq_b = (const float*)d_in[24];
  const float* nm_w1  = (const float*)d_in[25];
  const float* nm_b1  = (const float*)d_in[26];
  const float* nm_w2  = (const float*)d_in[27];
  const float* nm_b2  = (const float*)d_in[28];
  const float* noise  = (const float*)d_in[29];

  float* ws = (float*)d_ws;
  float* buf0  = ws;                        // 262144 floats
  float* buf1  = ws + 262144;               // 262144
  float* hnorm = ws + 524288;               // 131072
  float* hh    = ws + 655360;               // 131072
  float* nbuf  = ws + 786432;               // 131072
  float* ncon  = ws + 917504;               // 2048
  float* dcw   = ws + 919552;               // 2048
  double* P0g  = (double*)(ws + 921600);    // 4096*65 doubles (byte off %8==0)
  float4* segT = (float4*)(ws + 1454080);   // 4096*65 float4  (byte off %16==0)

  // upconv chain buffers (ping-pong, regions dead before reuse):
  float* u16  = buf1;                       // (B,128,16) = 65536
  float* u32  = buf0;                       // (B,128,32) = 131072
  float* u64b = buf1;                       // (B,128,64) = 262144 (u16 dead)
  float* y4   = buf0;                       // (B,128,64) = 262144 (u32 dead)

  k_A   <<<dim3(NB, 20), 256, 0, stream>>>(x, lin_w, lin_b, up_w0, up_b0, u16,
                                           noise, dcw);
  k_B   <<<dim3(NB, 8), 256, 0, stream>>>(u16, up_w1, up_b1, u32);
  k_C   <<<dim3(NB,16), 256, 0, stream>>>(u32, up_w2, up_b2, u64b);
  k_D   <<<dim3(NB,32), 256, 0, stream>>>(u64b, up_w3, up_b3, y4);
  k_s4n <<<dim3(NB,16), 256, 0, stream>>>(y4, fin_w, fin_b, hnorm);
  k_mm12<<<dim3(4, NB, 2), 256, 0, stream>>>(hnorm, hw1, hb1, hw2, hb2,
                                             tw1, tb1, tw2, tb2, hh, nbuf);
  k_afp <<<dim3(33, NB), 256, 0, stream>>>(hh, amp_w, amp_b, freq_w, freq_b,
                                           nbuf, nm_w1, nm_b1, nm_w2, nm_b2,
                                           dcw, P0g, segT, ncon);
  k_harm<<<dim3(64, NB), 256, 0, stream>>>(P0g, segT, ncon, (float*)d_out);
}

// Round 11
// 180.632 us; speedup vs baseline: 1.5955x; 1.0342x over previous
//
#include <hip/hip_runtime.h>
#include <math.h>

// DDSP-style Generator for MI355X.
// R1: split latency-bound k_heads -> 5 kernels. 407->246us.
// R3: split upconv monolith. 246->228us.
// R6: 8-kernel fusion w/ 32x upsample duplication -> 288us REGRESSION.
// R8: output-side upsample fix -> 228us. R9/R10: noise-DC parallelized -> 186.8us.
// R11: work reduction (fit: gap~4us/launch, work~155us = 3x issue-model => cut issued ops):
//   - k_harm all-f32 inner loop (P0 pre-reduced mod 1 in fp64 at k_afp, stored f32 P0r);
//     phase-delta in f32 is exact to ~6e-5 rad << 0.0156 absmax driver.
//   - k_C/k_D/k_s4n: 2 output channels per thread (share LDS reads + f64 cvts).
//   - Kt upsample matrices built ONCE in k_A spare block -> global; k_B/k_C load them.
// fp64 retained on everything feeding freq (5e4 amplification into tail phase).

static constexpr double PI_D     = 3.14159265358979323846;
static constexpr double LOWEST_D = 40.0 / 11025.0;
static constexpr double RT2O2    = 0.70710678118654752440;  // cos(pi/4)

#define NB    32
#define NFRM  64
#define NSMP  16384

// ---- k_A : g<4: lin -> ups4->8 -> conv w0 + leaky -> ups8->16.
//            g in 4..19: noise-DC. g==20 (b==0): build kmat16/kmat32 -> global ----
__global__ __launch_bounds__(256) void k_A(const float* __restrict__ x,
    const float* __restrict__ lw, const float* __restrict__ lb,
    const float* __restrict__ w0, const float* __restrict__ b0,
    float* __restrict__ u16,
    const float* __restrict__ noise, float* __restrict__ dcw,
    double* __restrict__ kmatg) {
  int b = blockIdx.x, g = blockIdx.y;
  int tid = threadIdx.x;
  if (g == 20) {                               // band-limited 2x upsample matrices
    if (b != 0) return;
    __shared__ double ct32[32], ct64[64];
    if (tid < 32) ct32[tid] = cos(PI_D*(double)tid/16.0);
    if (tid < 64) ct64[tid] = cos(PI_D*(double)tid/32.0);
    __syncthreads();
    for (int i = tid; i < 512; i += 256) {     // n=16 -> 32 : [j<16][m<32]
      int j = i >> 5, m = i & 31, dm = m - 2*j;
      double s = 1.0;
      #pragma unroll
      for (int k = 1; k <= 7; ++k) s += 2.0*ct32[(k*dm) & 31];
      double cm2 = (m & 1) ? 0.0 : ((m & 2) ? -1.0 : 1.0);
      s += 2.0*cm2*((j & 1) ? -1.0 : 1.0);
      kmatg[i] = s*(1.0/16.0);
    }
    for (int i = tid; i < 2048; i += 256) {    // n=32 -> 64 : [j<32][m<64]
      int j = i >> 6, m = i & 63, dm = m - 2*j;
      double s = 1.0;
      #pragma unroll
      for (int k = 1; k <= 15; ++k) s += 2.0*ct64[(k*dm) & 63];
      double cm2 = (m & 1) ? 0.0 : ((m & 2) ? -1.0 : 1.0);
      s += 2.0*cm2*((j & 1) ? -1.0 : 1.0);
      kmatg[512 + i] = s*(1.0/32.0);
    }
    return;
  }
  if (g >= 4) {                                // DC of noise windows: 1 wave = 1 frame
    int gp = g - 4;                            // 0..15
    int wv = tid >> 6, lane = tid & 63;
    int fr = gp*4 + wv;                        // 0..63
    const float* p = noise + ((size_t)b*NFRM + fr)*512;
    double s = 0.0;
    #pragma unroll
    for (int i = 0; i < 8; ++i) s += (double)p[lane + i*64];
    for (int off = 32; off > 0; off >>= 1) s += __shfl_down(s, off);
    if (lane == 0) dcw[b*NFRM + fr] = (float)s;
    return;
  }
  __shared__ float  xs[128];
  __shared__ float  lin[512];
  __shared__ float  u8[1024];                  // 128 ch x 8
  __shared__ float  y[256];                    // 32 ch x 8 conv out
  __shared__ double Kt16[128];                 // [j<8][m<16]
  __shared__ double ctab16[16];
  if (tid < 128) xs[tid] = x[b*128 + tid];
  if (tid < 16)  ctab16[tid] = cos(PI_D*(double)tid/8.0);
  __syncthreads();
  {
    double a0 = 0.0, a1 = 0.0;
    for (int l = 0; l < 128; ++l) {
      double xv = (double)xs[l];
      a0 += xv * (double)lw[(size_t)l*512 + tid];
      a1 += xv * (double)lw[(size_t)l*512 + tid + 256];
    }
    lin[tid]     = (float)(a0 + (double)lb[tid]);
    lin[tid+256] = (float)(a1 + (double)lb[tid+256]);
  }
  if (tid < 128) {                             // Kt16 for 8->16
    int j = tid >> 4, m = tid & 15;
    int dm = m - 2*j;
    double s = 1.0;
    #pragma unroll
    for (int k = 1; k <= 3; ++k) s += 2.0*ctab16[(k*dm) & 15];
    double cm2 = (m & 1) ? 0.0 : ((m & 2) ? -1.0 : 1.0);
    s += 2.0*cm2*((j & 1) ? -1.0 : 1.0);
    Kt16[j*16 + m] = s * 0.125;
  }
  __syncthreads();
  const double ct8[8] = {1.0, RT2O2, 0.0, -RT2O2, -1.0, -RT2O2, 0.0, RT2O2};
  #pragma unroll
  for (int rep = 0; rep < 4; ++rep) {          // ups4->8 (exact)
    int idx = tid + 256*rep;
    int c = idx >> 3, m = idx & 7;
    double cm2 = (m & 1) ? 0.0 : ((m & 2) ? -1.0 : 1.0);
    double a = 0.0;
    #pragma unroll
    for (int j = 0; j < 4; ++j) {
      double K = 0.25*(1.0 + 2.0*ct8[(m - 2*j) & 7] + 2.0*cm2*((j & 1) ? -1.0 : 1.0));
      a += K * (double)lin[c*4 + j];
    }
    u8[idx] = (float)a;
  }
  __syncthreads();
  int ol = tid >> 3, t = tid & 7;              // conv w0 @T=8
  int o = g*32 + ol;
  double a0 = 0.0, a1 = 0.0;
  const float* wp = w0 + (size_t)o*384;
  for (int c = 0; c < 128; ++c) {
    int base = c*8 + t;
    float xm = (t > 0) ? u8[base-1] : 0.f;
    float xc = u8[base];
    float xp = (t < 7) ? u8[base+1] : 0.f;
    a0 += (double)wp[c*3+0]*(double)xm + (double)wp[c*3+1]*(double)xc;
    a1 += (double)wp[c*3+2]*(double)xp;
  }
  float v = (float)(a0 + a1 + (double)b0[o]);
  y[tid] = (v > 0.f) ? v : 0.2f*v;
  __syncthreads();
  #pragma unroll
  for (int rep = 0; rep < 2; ++rep) {          // ups 8->16 of own channels
    int idx = tid + 256*rep;
    int c = idx >> 4, m = idx & 15;            // c 0..31
    double a = 0.0;
    #pragma unroll
    for (int j = 0; j < 8; ++j) a += Kt16[j*16 + m] * (double)y[c*8 + j];
    u16[((size_t)b*128 + g*32 + c)*16 + m] = (float)a;
  }
}

// ---- k_B : conv w1 @T=16 + leaky + ups16->32 (Kt from global) ----
__global__ __launch_bounds__(256) void k_B(const float* __restrict__ in,
    const float* __restrict__ w, const float* __restrict__ bias,
    float* __restrict__ u32, const double* __restrict__ kmatg) {
  int b = blockIdx.x, g = blockIdx.y;          // g 0..7 -> 16 out channels
  int tid = threadIdx.x;
  __shared__ float  u[128*16];
  __shared__ float  y[256];
  __shared__ double Kt[512];
  for (int i = tid; i < 2048; i += 256) u[i] = in[(size_t)b*2048 + i];
  for (int i = tid; i < 512; i += 256) Kt[i] = kmatg[i];
  __syncthreads();
  int ol = tid >> 4, t = tid & 15;
  int o = g*16 + ol;
  double a0 = 0.0, a1 = 0.0;
  const float* wp = w + (size_t)o*384;
  for (int c = 0; c < 128; ++c) {
    int base = c*16 + t;
    float xm = (t > 0)  ? u[base-1] : 0.f;
    float xc = u[base];
    float xp = (t < 15) ? u[base+1] : 0.f;
    a0 += (double)wp[c*3+0]*(double)xm + (double)wp[c*3+1]*(double)xc;
    a1 += (double)wp[c*3+2]*(double)xp;
  }
  float v = (float)(a0 + a1 + (double)bias[o]);
  y[tid] = (v > 0.f) ? v : 0.2f*v;
  __syncthreads();
  #pragma unroll
  for (int rep = 0; rep < 2; ++rep) {
    int idx = tid + 256*rep;
    int c = idx >> 5, m = idx & 31;            // c 0..15
    double a = 0.0;
    #pragma unroll
    for (int j = 0; j < 16; ++j) a += Kt[j*32 + m] * (double)y[c*16 + j];
    u32[((size_t)b*128 + g*16 + c)*32 + m] = (float)a;
  }
}

// ---- k_C : conv w2 @T=32 (2 o/thread) + leaky + ups32->64 (Kt from global) ----
__global__ __launch_bounds__(256) void k_C(const float* __restrict__ in,
    const float* __restrict__ w, const float* __restrict__ bias,
    float* __restrict__ u64o, const double* __restrict__ kmatg) {
  int b = blockIdx.x, g = blockIdx.y;          // g 0..7 -> 16 out channels
  int tid = threadIdx.x;
  __shared__ float  u[128*32];                 // 16KB
  __shared__ float  y[512];                    // 16 ch x 32
  __shared__ double Kt[2048];                  // 16KB
  for (int i = tid; i < 4096; i += 256) u[i] = in[(size_t)b*4096 + i];
  for (int i = tid; i < 2048; i += 256) Kt[i] = kmatg[512 + i];
  __syncthreads();
  int og = tid >> 5, t = tid & 31;             // og 0..7
  int o1 = g*16 + og, o2 = o1 + 8;
  double A0=0, A1=0, A2=0, B0=0, B1=0, B2=0;
  const float* w1 = w + (size_t)o1*384;
  const float* w2 = w + (size_t)o2*384;
  for (int c = 0; c < 128; ++c) {
    int base = c*32 + t;
    double xm = (double)((t > 0)  ? u[base-1] : 0.f);
    double xc = (double)u[base];
    double xp = (double)((t < 31) ? u[base+1] : 0.f);
    A0 += (double)w1[c*3+0]*xm; A1 += (double)w1[c*3+1]*xc; A2 += (double)w1[c*3+2]*xp;
    B0 += (double)w2[c*3+0]*xm; B1 += (double)w2[c*3+1]*xc; B2 += (double)w2[c*3+2]*xp;
  }
  float v1 = (float)(A0 + A1 + A2 + (double)bias[o1]);
  float v2 = (float)(B0 + B1 + B2 + (double)bias[o2]);
  y[og*32 + t]     = (v1 > 0.f) ? v1 : 0.2f*v1;
  y[(og+8)*32 + t] = (v2 > 0.f) ? v2 : 0.2f*v2;
  __syncthreads();
  #pragma unroll
  for (int rep = 0; rep < 4; ++rep) {          // ups: 16 ch x 64 m
    int idx = tid + 256*rep;
    int c = idx >> 6, m = idx & 63;
    double a = 0.0;
    #pragma unroll 8
    for (int j = 0; j < 32; ++j) a += Kt[j*64 + m] * (double)y[c*32 + j];
    u64o[((size_t)b*128 + g*16 + c)*64 + m] = (float)a;
  }
}

// ---- k_D : conv w3 @T=64 (2 o/thread) + leaky ----
__global__ __launch_bounds__(256) void k_D(const float* __restrict__ in,
    const float* __restrict__ w, const float* __restrict__ bias,
    float* __restrict__ y4) {
  int b = blockIdx.x, g = blockIdx.y;          // g 0..15 -> 8 out channels
  int tid = threadIdx.x;
  __shared__ float u[128*64];                  // 32KB
  for (int i = tid; i < 8192; i += 256) u[i] = in[(size_t)b*8192 + i];
  __syncthreads();
  int og = tid >> 6, t = tid & 63;
  int o1 = g*8 + og, o2 = o1 + 4;
  double A0=0, A1=0, A2=0, B0=0, B1=0, B2=0;
  const float* w1 = w + (size_t)o1*384;        // wave-uniform -> scalar loads
  const float* w2 = w + (size_t)o2*384;
  for (int c = 0; c < 128; ++c) {
    int base = c*64 + t;
    double xm = (double)((t > 0)  ? u[base-1] : 0.f);
    double xc = (double)u[base];
    double xp = (double)((t < 63) ? u[base+1] : 0.f);
    A0 += (double)w1[c*3+0]*xm; A1 += (double)w1[c*3+1]*xc; A2 += (double)w1[c*3+2]*xp;
    B0 += (double)w2[c*3+0]*xm; B1 += (double)w2[c*3+1]*xc; B2 += (double)w2[c*3+2]*xp;
  }
  float v1 = (float)(A0 + A1 + A2 + (double)bias[o1]);
  float v2 = (float)(B0 + B1 + B2 + (double)bias[o2]);
  y4[((size_t)b*128 + o1)*64 + t] = (v1 > 0.f) ? v1 : 0.2f*v1;
  y4[((size_t)b*128 + o2)*64 + t] = (v2 > 0.f) ? v2 : 0.2f*v2;
}

// ---- k_s4n : final conv3 (2 o/thread) + instance-norm (wave = t-row of each o) ----
__global__ __launch_bounds__(256) void k_s4n(const float* __restrict__ in,
    const float* __restrict__ fw, const float* __restrict__ fb,
    float* __restrict__ hnorm) {
  int b = blockIdx.x, g = blockIdx.y;          // g 0..7 -> 8 out channels
  int tid = threadIdx.x;
  __shared__ float uu[128*64];
  for (int i = tid; i < 8192; i += 256) uu[i] = in[(size_t)b*8192 + i];
  __syncthreads();
  int og = tid >> 6, t = tid & 63;
  int o1 = g*8 + og, o2 = o1 + 4;
  double A0=0, A1=0, A2=0, B0=0, B1=0, B2=0;
  const float* w1 = fw + (size_t)o1*384;
  const float* w2 = fw + (size_t)o2*384;
  for (int c = 0; c < 128; ++c) {
    int base = c*64 + t;
    double xm = (double)((t > 0)  ? uu[base-1] : 0.f);
    double xc = (double)uu[base];
    double xp = (double)((t < 63) ? uu[base+1] : 0.f);
    A0 += (double)w1[c*3+0]*xm; A1 += (double)w1[c*3+1]*xc; A2 += (double)w1[c*3+2]*xp;
    B0 += (double)w2[c*3+0]*xm; B1 += (double)w2[c*3+1]*xc; B2 += (double)w2[c*3+2]*xp;
  }
  float vf1 = (float)(A0 + A1 + A2 + (double)fb[o1]);
  float vf2 = (float)(B0 + B1 + B2 + (double)fb[o2]);
  double s1 = (double)vf1, s2 = (double)vf2;
  for (int off = 32; off > 0; off >>= 1) { s1 += __shfl_down(s1, off); s2 += __shfl_down(s2, off); }
  double m1 = __shfl(s1, 0) * (1.0/64.0);
  double m2 = __shfl(s2, 0) * (1.0/64.0);
  double d1 = (double)vf1 - m1, d2 = (double)vf2 - m2;
  double q1 = d1*d1, q2 = d2*d2;
  for (int off = 32; off > 0; off >>= 1) { q1 += __shfl_down(q1, off); q2 += __shfl_down(q2, off); }
  double v1 = __shfl(q1, 0) * (1.0/64.0);
  double v2 = __shfl(q2, 0) * (1.0/64.0);
  hnorm[((size_t)b*64 + o1)*64 + t] = (float)(d1 * (1.0/sqrt(v1 + 1e-5)));
  hnorm[((size_t)b*64 + o2)*64 + t] = (float)(d2 * (1.0/sqrt(v2 + 1e-5)));
}

// ---- k_mm12 : both 1x1-conv layers; block = (16 t-cols, b, chain z) ----
__global__ __launch_bounds__(256) void k_mm12(const float* __restrict__ hn,
    const float* __restrict__ hw1, const float* __restrict__ hb1,
    const float* __restrict__ hw2, const float* __restrict__ hb2,
    const float* __restrict__ tw1, const float* __restrict__ tb1,
    const float* __restrict__ tw2, const float* __restrict__ tb2,
    float* __restrict__ hh, float* __restrict__ nbuf) {
  int tq = blockIdx.x, b = blockIdx.y, z = blockIdx.z;
  int tid = threadIdx.x;
  const float* W1 = z ? tw1 : hw1; const float* B1 = z ? tb1 : hb1;
  const float* W2 = z ? tw2 : hw2; const float* B2 = z ? tb2 : hb2;
  __shared__ float h0[64*16];
  __shared__ float t1[64*16];
  for (int i = tid; i < 1024; i += 256) {
    int c = i >> 4, tt = i & 15;
    h0[i] = hn[((size_t)b*64 + c)*64 + tq*16 + tt];
  }
  __syncthreads();
  int t = tid & 15, ob = tid >> 4;             // ob 0..15, 4 o's per thread
  #pragma unroll
  for (int k = 0; k < 4; ++k) {
    int o = ob + 16*k;
    double a0 = 0.0, a1 = 0.0;
    const float* wp = W1 + o*64;
    for (int c = 0; c < 64; c += 2) {
      a0 += (double)wp[c]  *(double)h0[c*16 + t];
      a1 += (double)wp[c+1]*(double)h0[(c+1)*16 + t];
    }
    float v = (float)(a0 + a1 + (double)B1[o]);
    v = (v > 0.f) ? v : 0.2f*v;
    t1[o*16 + t] = v;
  }
  __syncthreads();
  float* out = z ? nbuf : hh;
  #pragma unroll
  for (int k = 0; k < 4; ++k) {
    int o = ob + 16*k;
    double a0 = 0.0, a1 = 0.0;
    const float* wp = W2 + o*64;
    for (int c = 0; c < 64; c += 2) {
      a0 += (double)wp[c]  *(double)t1[c*16 + t];
      a1 += (double)wp[c+1]*(double)t1[(c+1)*16 + t];
    }
    out[((size_t)b*64 + o)*64 + tq*16 + t] = (float)(a0 + a1 + (double)B2[o]);
  }
}

// ---- k_afp : amp/freq heads + fp64 shfl-scan prefix -> f32 P0r (mod 1) + segT (g<32);
//              veff/ncon (g==32) ----
__global__ __launch_bounds__(256) void k_afp(const float* __restrict__ hh,
    const float* __restrict__ amp_w, const float* __restrict__ amp_b,
    const float* __restrict__ freq_w, const float* __restrict__ freq_b,
    const float* __restrict__ nbuf,
    const float* __restrict__ nm_w1, const float* __restrict__ nm_b1,
    const float* __restrict__ nm_w2, const float* __restrict__ nm_b2,
    const float* __restrict__ dcw,
    float* __restrict__ P0r, float4* __restrict__ segT,
    float* __restrict__ ncon) {
  int g = blockIdx.x, b = blockIdx.y;
  int tid = threadIdx.x;
  if (g < 32) {
    int ow = tid >> 6;                         // wave -> oscillator
    int o = g*4 + ow;
    int lane = tid & 63;                       // frame j
    const float* X  = hh + (size_t)b*4096 + lane;
    const float* wa = amp_w + o*64;
    const float* wf = freq_w + o*64;
    double za = (double)amp_b[o], zf = (double)freq_b[o];
    for (int c = 0; c < 64; ++c) {
      double hv = (double)X[(size_t)c*64];
      za += (double)wa[c]*hv;
      zf += (double)wf[c]*hv;
    }
    float a = fabsf((float)za);
    double sg = 1.0/(1.0 + exp(-zf));
    float f = (float)(LOWEST_D + sg*sg*(1.0 - LOWEST_D));
    double F = (double)f;                      // inclusive scan over 64 lanes
    #pragma unroll
    for (int off = 1; off < 64; off <<= 1) {
      double n = __shfl_up(F, off);
      if (lane >= off) F += n;
    }
    double Fm1 = __shfl_up(F, 1); if (lane < 1) Fm1 = 0.0;
    double Fm2 = __shfl_up(F, 2); if (lane < 2) Fm2 = 0.0;
    float fm1 = __shfl_up(f, 1);
    float am1 = __shfl_up(a, 1);
    size_t row = ((size_t)b*128 + o)*65;
    double P = (lane == 0) ? 0.0 : 64.0*(Fm1 + Fm2);
    P0r[row + lane] = (float)(P - floor(P));   // phase mod 1 rev, f32 is enough downstream
    segT[row + lane] = (lane == 0) ? make_float4(f, 0.f, a, 0.f)
                                   : make_float4(fm1, f - fm1, am1, a - am1);
    if (lane == 63) {
      double P64 = 64.0*(F + Fm1);
      P0r[row + 64]  = (float)(P64 - floor(P64));
      segT[row + 64] = make_float4(f, 0.f, a, 0.f);
    }
  } else {
    __shared__ double veff[64];
    if (tid < 64) {                            // veff[m] = sum_c nm_w2[0,c]*nm_w1[c,m]
      double a = 0.0;
      for (int c = 0; c < 128; ++c) a += (double)nm_w2[c]*(double)nm_w1[c*64 + tid];
      veff[tid] = a;
    }
    __syncthreads();
    if (tid < 64) {
      double beff = (double)nm_b2[0];
      for (int c = 0; c < 128; ++c) beff += (double)nm_w2[c]*(double)nm_b1[c];
      int fr = tid;
      double s0 = beff;
      for (int m = 0; m < 64; ++m) s0 += veff[m]*(double)nbuf[((size_t)b*64 + m)*64 + fr];
      ncon[b*NFRM + fr] = (float)((double)dcw[b*NFRM + fr]*s0*(1.0/512.0));
    }
  }
}

// ---- k_harm : block = (q,b): 256 samples x 128 oscillators. ALL-f32 inner loop. ----
// rev = P0r + c1*f + c2*df (f32, <=193 rev, err ~1e-5 rev = 6e-5 rad), fract -> v_sin_f32.
__global__ __launch_bounds__(256) void k_harm(const float* __restrict__ P0r,
                                              const float4* __restrict__ segT,
                                              const float* __restrict__ nc,
                                              float* __restrict__ outp) {
  int q = blockIdx.x;                          // 0..63
  int b = blockIdx.y;
  int tid = threadIdx.x;
  __shared__ float  P0s[256];                  // [half][osc]
  __shared__ float4 segs[256];
  int half = tid >> 7;
  int osc  = tid & 127;
  {
    size_t row = ((size_t)b*128 + osc)*65 + (q + half);
    P0s[tid]  = P0r[row];
    segs[tid] = segT[row];
  }
  __syncthreads();

  int j = q + half;
  int s = q*256 + tid;
  int r = (j == 0) ? s : (s - (256*j - 128));
  float w0 = (j == 0 || j == 64) ? 0.f : (1.f/512.f);
  float rp = (float)(r + 1);
  float c1 = rp * 0.5f;
  float c2 = (rp*w0 + (float)r*rp*(1.f/512.f)) * 0.5f;   // exact in f32
  float wr = w0 + (float)r*(1.f/256.f);

  const float*  P0p = P0s + half*128;
  const float4* sp  = segs + half*128;
  float acc = 0.f;
  #pragma unroll 4
  for (int o = 0; o < 128; ++o) {
    float4 sg = sp[o];                         // {f_lo, df, a_lo, da} uniform broadcast
    float rev = fmaf(c2, sg.y, fmaf(c1, sg.x, P0p[o]));
    rev = rev - floorf(rev);
    float sv = __builtin_amdgcn_sinf(rev);     // sin(2*pi*x)
    float am = fmaf(sg.w, wr, sg.z);
    acc = fmaf(sv, am, acc);
  }
  float ns = nc[b*NFRM + q] + ((q > 0) ? nc[b*NFRM + q - 1] : 0.f);
  outp[(size_t)b*NSMP + s] = acc + ns;
}

// ---------------------------------------------------------------------------
extern "C" void kernel_launch(void* const* d_in, const int* in_sizes, int n_in,
                              void* d_out, int out_size, void* d_ws, size_t ws_size,
                              hipStream_t stream) {
  (void)in_sizes; (void)n_in; (void)out_size; (void)ws_size;
  const float* x      = (const float*)d_in[0];
  const float* lin_w  = (const float*)d_in[1];
  const float* lin_b  = (const float*)d_in[2];
  const float* up_w0  = (const float*)d_in[3];
  const float* up_b0  = (const float*)d_in[4];
  const float* up_w1  = (const float*)d_in[5];
  const float* up_b1  = (const float*)d_in[6];
  const float* up_w2  = (const float*)d_in[7];
  const float* up_b2  = (const float*)d_in[8];
  const float* up_w3  = (const float*)d_in[9];
  const float* up_b3  = (const float*)d_in[10];
  const float* fin_w  = (const float*)d_in[11];
  const float* fin_b  = (const float*)d_in[12];
  const float* hw1    = (const float*)d_in[13];
  const float* hb1    = (const float*)d_in[14];
  const float* hw2    = (const float*)d_in[15];
  const float* hb2    = (const float*)d_in[16];
  const float* tw1    = (const float*)d_in[17];
  const float* tb1    = (const float*)d_in[18];
  const float* tw2    = (const float*)d_in[19];
  const float* tb2    = (const float*)d_in[20];
  const float* amp_w  = (const float*)d_in[21];
  const float* amp_b  = (const float*)d_in[22];
  const float* freq_w = (const float*)d_in[23];
  const float* freq_b = (const float*)d_in[24];
  const float* nm_w1  = (const float*)d_in[25];
  const float* nm_b1  = (const float*)d_in[26];
  const float* nm_w2  = (const float*)d_in[27];
  const float* nm_b2  = (const float*)d_in[28];
  const float* noise  = (const float*)d_in[29];

  float* ws = (float*)d_ws;
  float* buf0  = ws;                        // 262144 floats
  float* buf1  = ws + 262144;               // 262144
  float* hnorm = ws + 524288;               // 131072
  float* hh    = ws + 655360;               // 131072
  float* nbuf  = ws + 786432;               // 131072
  float* ncon  = ws + 917504;               // 2048
  float* dcw   = ws + 919552;               // 2048
  double* kmatg = (double*)(ws + 921600);   // 2560 doubles (byte off %8==0)
  float* P0r   = ws + 926720;               // 4096*65 floats
  float4* segT = (float4*)(ws + 1192960);   // 4096*65 float4 (byte off %16==0)

  // upconv chain buffers (ping-pong, regions dead before reuse):
  float* u16  = buf1;                       // (B,128,16) = 65536
  float* u32  = buf0;                       // (B,128,32) = 131072
  float* u64b = buf1;                       // (B,128,64) = 262144 (u16 dead)
  float* y4   = buf0;                       // (B,128,64) = 262144 (u32 dead)

  k_A   <<<dim3(NB, 21), 256, 0, stream>>>(x, lin_w, lin_b, up_w0, up_b0, u16,
                                           noise, dcw, kmatg);
  k_B   <<<dim3(NB, 8), 256, 0, stream>>>(u16, up_w1, up_b1, u32, kmatg);
  k_C   <<<dim3(NB, 8), 256, 0, stream>>>(u32, up_w2, up_b2, u64b, kmatg);
  k_D   <<<dim3(NB,16), 256, 0, stream>>>(u64b, up_w3, up_b3, y4);
  k_s4n <<<dim3(NB, 8), 256, 0, stream>>>(y4, fin_w, fin_b, hnorm);
  k_mm12<<<dim3(4, NB, 2), 256, 0, stream>>>(hnorm, hw1, hb1, hw2, hb2,
                                             tw1, tb1, tw2, tb2, hh, nbuf);
  k_afp <<<dim3(33, NB), 256, 0, stream>>>(hh, amp_w, amp_b, freq_w, freq_b,
                                           nbuf, nm_w1, nm_b1, nm_w2, nm_b2,
                                           dcw, P0r, segT, ncon);
  k_harm<<<dim3(64, NB), 256, 0, stream>>>(P0r, segT, ncon, (float*)d_out);
}

// Round 12
// 178.114 us; speedup vs baseline: 1.6181x; 1.0141x over previous
//
#include <hip/hip_runtime.h>
#include <math.h>

// DDSP-style Generator for MI355X.
// R1: split k_heads. 407->246. R3: split upconv. ->228. R6: bad fusion ->288.
// R8: output-side upsample ->228. R9/R10: noise-DC parallel ->186.8.
// R11: f32 k_harm inner loop + 2o/thread convs + global Kt ->180.6.
//      Profile: k_A=42.8us, VALUBusy 4.8% -- serial per-iteration global weight
//      loads at <=1 block/CU (lin: 256 dependent HBM loads/thread; w0: 3/c-iter).
// R12: cooperative LDS staging of ALL weight streams (batched coalesced float4,
//      latency paid once, inner loops read LDS broadcast): lw in 16-row chunks,
//      w0/w1/w2/w3/fin rows at stride 385, mm12 W1/W2 at stride 65.
//      Accumulation order unchanged -> numerics identical to R11.
// fp64 retained on everything feeding freq (5e4 amplification into tail phase).

static constexpr double PI_D     = 3.14159265358979323846;
static constexpr double LOWEST_D = 40.0 / 11025.0;
static constexpr double RT2O2    = 0.70710678118654752440;  // cos(pi/4)

#define NB    32
#define NFRM  64
#define NSMP  16384

// ---- k_A : g<4: lin -> ups4->8 -> conv w0 + leaky -> ups8->16.
//            g in 4..19: noise-DC. g==20 (b==0): build kmat16/kmat32 -> global ----
__global__ __launch_bounds__(256) void k_A(const float* __restrict__ x,
    const float* __restrict__ lw, const float* __restrict__ lb,
    const float* __restrict__ w0, const float* __restrict__ b0,
    float* __restrict__ u16,
    const float* __restrict__ noise, float* __restrict__ dcw,
    double* __restrict__ kmatg) {
  int b = blockIdx.x, g = blockIdx.y;
  int tid = threadIdx.x;
  if (g == 20) {                               // band-limited 2x upsample matrices
    if (b != 0) return;
    __shared__ double ct32[32], ct64[64];
    if (tid < 32) ct32[tid] = cos(PI_D*(double)tid/16.0);
    if (tid < 64) ct64[tid] = cos(PI_D*(double)tid/32.0);
    __syncthreads();
    for (int i = tid; i < 512; i += 256) {     // n=16 -> 32 : [j<16][m<32]
      int j = i >> 5, m = i & 31, dm = m - 2*j;
      double s = 1.0;
      #pragma unroll
      for (int k = 1; k <= 7; ++k) s += 2.0*ct32[(k*dm) & 31];
      double cm2 = (m & 1) ? 0.0 : ((m & 2) ? -1.0 : 1.0);
      s += 2.0*cm2*((j & 1) ? -1.0 : 1.0);
      kmatg[i] = s*(1.0/16.0);
    }
    for (int i = tid; i < 2048; i += 256) {    // n=32 -> 64 : [j<32][m<64]
      int j = i >> 6, m = i & 63, dm = m - 2*j;
      double s = 1.0;
      #pragma unroll
      for (int k = 1; k <= 15; ++k) s += 2.0*ct64[(k*dm) & 63];
      double cm2 = (m & 1) ? 0.0 : ((m & 2) ? -1.0 : 1.0);
      s += 2.0*cm2*((j & 1) ? -1.0 : 1.0);
      kmatg[512 + i] = s*(1.0/32.0);
    }
    return;
  }
  if (g >= 4) {                                // DC of noise windows: 1 wave = 1 frame
    int gp = g - 4;                            // 0..15
    int wv = tid >> 6, lane = tid & 63;
    int fr = gp*4 + wv;                        // 0..63
    const float* p = noise + ((size_t)b*NFRM + fr)*512;
    double s = 0.0;
    #pragma unroll
    for (int i = 0; i < 8; ++i) s += (double)p[lane + i*64];
    for (int off = 32; off > 0; off >>= 1) s += __shfl_down(s, off);
    if (lane == 0) dcw[b*NFRM + fr] = (float)s;
    return;
  }
  __shared__ float  xs[128];
  __shared__ float  lin[512];
  __shared__ float  lwc[16*512];               // 32KB lw chunk
  __shared__ float  wl0[32*385];               // 49KB w0 rows (stride 385)
  __shared__ float  u8[1024];                  // 128 ch x 8
  __shared__ float  y[256];                    // 32 ch x 8 conv out
  __shared__ double Kt16[128];                 // [j<8][m<16]
  __shared__ double ctab16[16];
  if (tid < 128) xs[tid] = x[b*128 + tid];
  if (tid < 16)  ctab16[tid] = cos(PI_D*(double)tid/8.0);
  {
    int o0 = g*32;                             // stage w0 rows, coalesced
    for (int i = tid; i < 32*384; i += 256) {
      int oi = i/384, r = i - oi*384;
      wl0[oi*385 + r] = w0[(size_t)(o0+oi)*384 + r];
    }
  }
  __syncthreads();
  if (tid < 128) {                             // Kt16 for 8->16
    int j = tid >> 4, m = tid & 15;
    int dm = m - 2*j;
    double s = 1.0;
    #pragma unroll
    for (int k = 1; k <= 3; ++k) s += 2.0*ctab16[(k*dm) & 15];
    double cm2 = (m & 1) ? 0.0 : ((m & 2) ? -1.0 : 1.0);
    s += 2.0*cm2*((j & 1) ? -1.0 : 1.0);
    Kt16[j*16 + m] = s * 0.125;
  }
  // lin: lw staged in 8 chunks of 16 rows x 512 cols; acc order = l ascending (unchanged)
  double a0 = 0.0, a1 = 0.0;
  for (int ch = 0; ch < 8; ++ch) {
    const float4* src = (const float4*)(lw + (size_t)ch*8192);
    float4* dst = (float4*)lwc;
    for (int i = tid; i < 2048; i += 256) dst[i] = src[i];   // 8 indep float4/thread
    __syncthreads();
    #pragma unroll
    for (int r2 = 0; r2 < 16; ++r2) {
      double xv = (double)xs[ch*16 + r2];
      a0 += xv * (double)lwc[r2*512 + tid];
      a1 += xv * (double)lwc[r2*512 + tid + 256];
    }
    __syncthreads();
  }
  lin[tid]     = (float)(a0 + (double)lb[tid]);
  lin[tid+256] = (float)(a1 + (double)lb[tid+256]);
  __syncthreads();
  const double ct8[8] = {1.0, RT2O2, 0.0, -RT2O2, -1.0, -RT2O2, 0.0, RT2O2};
  #pragma unroll
  for (int rep = 0; rep < 4; ++rep) {          // ups4->8 (exact)
    int idx = tid + 256*rep;
    int c = idx >> 3, m = idx & 7;
    double cm2 = (m & 1) ? 0.0 : ((m & 2) ? -1.0 : 1.0);
    double a = 0.0;
    #pragma unroll
    for (int j = 0; j < 4; ++j) {
      double K = 0.25*(1.0 + 2.0*ct8[(m - 2*j) & 7] + 2.0*cm2*((j & 1) ? -1.0 : 1.0));
      a += K * (double)lin[c*4 + j];
    }
    u8[idx] = (float)a;
  }
  __syncthreads();
  int ol = tid >> 3, t = tid & 7;              // conv w0 @T=8, weights from LDS
  double A0 = 0.0, A1 = 0.0;
  const float* wr = wl0 + ol*385;
  for (int c = 0; c < 128; ++c) {
    int base = c*8 + t;
    float xm = (t > 0) ? u8[base-1] : 0.f;
    float xc = u8[base];
    float xp = (t < 7) ? u8[base+1] : 0.f;
    A0 += (double)wr[c*3+0]*(double)xm + (double)wr[c*3+1]*(double)xc;
    A1 += (double)wr[c*3+2]*(double)xp;
  }
  float v = (float)(A0 + A1 + (double)b0[g*32 + ol]);
  y[tid] = (v > 0.f) ? v : 0.2f*v;
  __syncthreads();
  #pragma unroll
  for (int rep = 0; rep < 2; ++rep) {          // ups 8->16 of own channels
    int idx = tid + 256*rep;
    int c = idx >> 4, m = idx & 15;            // c 0..31
    double a = 0.0;
    #pragma unroll
    for (int j = 0; j < 8; ++j) a += Kt16[j*16 + m] * (double)y[c*8 + j];
    u16[((size_t)b*128 + g*32 + c)*16 + m] = (float)a;
  }
}

// ---- k_B : conv w1 @T=16 + leaky + ups16->32 (Kt + weights staged in LDS) ----
__global__ __launch_bounds__(256) void k_B(const float* __restrict__ in,
    const float* __restrict__ w, const float* __restrict__ bias,
    float* __restrict__ u32, const double* __restrict__ kmatg) {
  int b = blockIdx.x, g = blockIdx.y;          // g 0..7 -> 16 out channels
  int tid = threadIdx.x;
  __shared__ float  u[128*16];
  __shared__ float  y[256];
  __shared__ double Kt[512];
  __shared__ float  wl[16*385];
  for (int i = tid; i < 2048; i += 256) u[i] = in[(size_t)b*2048 + i];
  for (int i = tid; i < 512; i += 256) Kt[i] = kmatg[i];
  for (int i = tid; i < 16*384; i += 256) {
    int oi = i/384, r = i - oi*384;
    wl[oi*385 + r] = w[(size_t)(g*16+oi)*384 + r];
  }
  __syncthreads();
  int ol = tid >> 4, t = tid & 15;
  int o = g*16 + ol;
  double a0 = 0.0, a1 = 0.0;
  const float* wr = wl + ol*385;
  for (int c = 0; c < 128; ++c) {
    int base = c*16 + t;
    float xm = (t > 0)  ? u[base-1] : 0.f;
    float xc = u[base];
    float xp = (t < 15) ? u[base+1] : 0.f;
    a0 += (double)wr[c*3+0]*(double)xm + (double)wr[c*3+1]*(double)xc;
    a1 += (double)wr[c*3+2]*(double)xp;
  }
  float v = (float)(a0 + a1 + (double)bias[o]);
  y[tid] = (v > 0.f) ? v : 0.2f*v;
  __syncthreads();
  #pragma unroll
  for (int rep = 0; rep < 2; ++rep) {
    int idx = tid + 256*rep;
    int c = idx >> 5, m = idx & 31;            // c 0..15
    double a = 0.0;
    #pragma unroll
    for (int j = 0; j < 16; ++j) a += Kt[j*32 + m] * (double)y[c*16 + j];
    u32[((size_t)b*128 + g*16 + c)*32 + m] = (float)a;
  }
}

// ---- k_C : conv w2 @T=32 (2 o/thread) + leaky + ups32->64 (Kt + weights in LDS) ----
__global__ __launch_bounds__(256) void k_C(const float* __restrict__ in,
    const float* __restrict__ w, const float* __restrict__ bias,
    float* __restrict__ u64o, const double* __restrict__ kmatg) {
  int b = blockIdx.x, g = blockIdx.y;          // g 0..7 -> 16 out channels
  int tid = threadIdx.x;
  __shared__ float  u[128*32];                 // 16KB
  __shared__ float  y[512];                    // 16 ch x 32
  __shared__ double Kt[2048];                  // 16KB
  __shared__ float  wl[16*385];                // 24.6KB
  for (int i = tid; i < 4096; i += 256) u[i] = in[(size_t)b*4096 + i];
  for (int i = tid; i < 2048; i += 256) Kt[i] = kmatg[512 + i];
  for (int i = tid; i < 16*384; i += 256) {
    int oi = i/384, r = i - oi*384;
    wl[oi*385 + r] = w[(size_t)(g*16+oi)*384 + r];
  }
  __syncthreads();
  int og = tid >> 5, t = tid & 31;             // og 0..7
  int o1 = g*16 + og, o2 = o1 + 8;
  double A0=0, A1=0, A2=0, B0=0, B1=0, B2=0;
  const float* w1 = wl + og*385;
  const float* w2 = wl + (og+8)*385;
  for (int c = 0; c < 128; ++c) {
    int base = c*32 + t;
    double xm = (double)((t > 0)  ? u[base-1] : 0.f);
    double xc = (double)u[base];
    double xp = (double)((t < 31) ? u[base+1] : 0.f);
    A0 += (double)w1[c*3+0]*xm; A1 += (double)w1[c*3+1]*xc; A2 += (double)w1[c*3+2]*xp;
    B0 += (double)w2[c*3+0]*xm; B1 += (double)w2[c*3+1]*xc; B2 += (double)w2[c*3+2]*xp;
  }
  float v1 = (float)(A0 + A1 + A2 + (double)bias[o1]);
  float v2 = (float)(B0 + B1 + B2 + (double)bias[o2]);
  y[og*32 + t]     = (v1 > 0.f) ? v1 : 0.2f*v1;
  y[(og+8)*32 + t] = (v2 > 0.f) ? v2 : 0.2f*v2;
  __syncthreads();
  #pragma unroll
  for (int rep = 0; rep < 4; ++rep) {          // ups: 16 ch x 64 m
    int idx = tid + 256*rep;
    int c = idx >> 6, m = idx & 63;
    double a = 0.0;
    #pragma unroll 8
    for (int j = 0; j < 32; ++j) a += Kt[j*64 + m] * (double)y[c*32 + j];
    u64o[((size_t)b*128 + g*16 + c)*64 + m] = (float)a;
  }
}

// ---- k_D : conv w3 @T=64 (2 o/thread) + leaky (weights in LDS) ----
__global__ __launch_bounds__(256) void k_D(const float* __restrict__ in,
    const float* __restrict__ w, const float* __restrict__ bias,
    float* __restrict__ y4) {
  int b = blockIdx.x, g = blockIdx.y;          // g 0..15 -> 8 out channels
  int tid = threadIdx.x;
  __shared__ float u[128*64];                  // 32KB
  __shared__ float wl[8*385];                  // 12.3KB
  for (int i = tid; i < 8192; i += 256) u[i] = in[(size_t)b*8192 + i];
  for (int i = tid; i < 8*384; i += 256) {
    int oi = i/384, r = i - oi*384;
    wl[oi*385 + r] = w[(size_t)(g*8+oi)*384 + r];
  }
  __syncthreads();
  int og = tid >> 6, t = tid & 63;
  int o1 = g*8 + og, o2 = o1 + 4;
  double A0=0, A1=0, A2=0, B0=0, B1=0, B2=0;
  const float* w1 = wl + og*385;
  const float* w2 = wl + (og+4)*385;
  for (int c = 0; c < 128; ++c) {
    int base = c*64 + t;
    double xm = (double)((t > 0)  ? u[base-1] : 0.f);
    double xc = (double)u[base];
    double xp = (double)((t < 63) ? u[base+1] : 0.f);
    A0 += (double)w1[c*3+0]*xm; A1 += (double)w1[c*3+1]*xc; A2 += (double)w1[c*3+2]*xp;
    B0 += (double)w2[c*3+0]*xm; B1 += (double)w2[c*3+1]*xc; B2 += (double)w2[c*3+2]*xp;
  }
  float v1 = (float)(A0 + A1 + A2 + (double)bias[o1]);
  float v2 = (float)(B0 + B1 + B2 + (double)bias[o2]);
  y4[((size_t)b*128 + o1)*64 + t] = (v1 > 0.f) ? v1 : 0.2f*v1;
  y4[((size_t)b*128 + o2)*64 + t] = (v2 > 0.f) ? v2 : 0.2f*v2;
}

// ---- k_s4n : final conv3 (2 o/thread) + instance-norm (weights in LDS) ----
__global__ __launch_bounds__(256) void k_s4n(const float* __restrict__ in,
    const float* __restrict__ fw, const float* __restrict__ fb,
    float* __restrict__ hnorm) {
  int b = blockIdx.x, g = blockIdx.y;          // g 0..7 -> 8 out channels
  int tid = threadIdx.x;
  __shared__ float uu[128*64];
  __shared__ float wl[8*385];
  for (int i = tid; i < 8192; i += 256) uu[i] = in[(size_t)b*8192 + i];
  for (int i = tid; i < 8*384; i += 256) {
    int oi = i/384, r = i - oi*384;
    wl[oi*385 + r] = fw[(size_t)(g*8+oi)*384 + r];
  }
  __syncthreads();
  int og = tid >> 6, t = tid & 63;
  int o1 = g*8 + og, o2 = o1 + 4;
  double A0=0, A1=0, A2=0, B0=0, B1=0, B2=0;
  const float* w1 = wl + og*385;
  const float* w2 = wl + (og+4)*385;
  for (int c = 0; c < 128; ++c) {
    int base = c*64 + t;
    double xm = (double)((t > 0)  ? uu[base-1] : 0.f);
    double xc = (double)uu[base];
    double xp = (double)((t < 63) ? uu[base+1] : 0.f);
    A0 += (double)w1[c*3+0]*xm; A1 += (double)w1[c*3+1]*xc; A2 += (double)w1[c*3+2]*xp;
    B0 += (double)w2[c*3+0]*xm; B1 += (double)w2[c*3+1]*xc; B2 += (double)w2[c*3+2]*xp;
  }
  float vf1 = (float)(A0 + A1 + A2 + (double)fb[o1]);
  float vf2 = (float)(B0 + B1 + B2 + (double)fb[o2]);
  double s1 = (double)vf1, s2 = (double)vf2;
  for (int off = 32; off > 0; off >>= 1) { s1 += __shfl_down(s1, off); s2 += __shfl_down(s2, off); }
  double m1 = __shfl(s1, 0) * (1.0/64.0);
  double m2 = __shfl(s2, 0) * (1.0/64.0);
  double d1 = (double)vf1 - m1, d2 = (double)vf2 - m2;
  double q1 = d1*d1, q2 = d2*d2;
  for (int off = 32; off > 0; off >>= 1) { q1 += __shfl_down(q1, off); q2 += __shfl_down(q2, off); }
  double v1 = __shfl(q1, 0) * (1.0/64.0);
  double v2 = __shfl(q2, 0) * (1.0/64.0);
  hnorm[((size_t)b*64 + o1)*64 + t] = (float)(d1 * (1.0/sqrt(v1 + 1e-5)));
  hnorm[((size_t)b*64 + o2)*64 + t] = (float)(d2 * (1.0/sqrt(v2 + 1e-5)));
}

// ---- k_mm12 : both 1x1-conv layers; W1/W2 staged in LDS (stride 65) ----
__global__ __launch_bounds__(256) void k_mm12(const float* __restrict__ hn,
    const float* __restrict__ hw1, const float* __restrict__ hb1,
    const float* __restrict__ hw2, const float* __restrict__ hb2,
    const float* __restrict__ tw1, const float* __restrict__ tb1,
    const float* __restrict__ tw2, const float* __restrict__ tb2,
    float* __restrict__ hh, float* __restrict__ nbuf) {
  int tq = blockIdx.x, b = blockIdx.y, z = blockIdx.z;
  int tid = threadIdx.x;
  const float* W1 = z ? tw1 : hw1; const float* B1 = z ? tb1 : hb1;
  const float* W2 = z ? tw2 : hw2; const float* B2 = z ? tb2 : hb2;
  __shared__ float h0[64*16];
  __shared__ float t1[64*16];
  __shared__ float w1l[64*65];
  __shared__ float w2l[64*65];
  for (int i = tid; i < 1024; i += 256) {
    int c = i >> 4, tt = i & 15;
    h0[i] = hn[((size_t)b*64 + c)*64 + tq*16 + tt];
  }
  for (int i = tid; i < 4096; i += 256) {
    int o = i >> 6, c = i & 63;
    w1l[o*65 + c] = W1[i];
    w2l[o*65 + c] = W2[i];
  }
  __syncthreads();
  int t = tid & 15, ob = tid >> 4;             // ob 0..15, 4 o's per thread
  #pragma unroll
  for (int k = 0; k < 4; ++k) {
    int o = ob + 16*k;
    double a0 = 0.0, a1 = 0.0;
    const float* wp = w1l + o*65;
    for (int c = 0; c < 64; c += 2) {
      a0 += (double)wp[c]  *(double)h0[c*16 + t];
      a1 += (double)wp[c+1]*(double)h0[(c+1)*16 + t];
    }
    float v = (float)(a0 + a1 + (double)B1[o]);
    v = (v > 0.f) ? v : 0.2f*v;
    t1[o*16 + t] = v;
  }
  __syncthreads();
  float* out = z ? nbuf : hh;
  #pragma unroll
  for (int k = 0; k < 4; ++k) {
    int o = ob + 16*k;
    double a0 = 0.0, a1 = 0.0;
    const float* wp = w2l + o*65;
    for (int c = 0; c < 64; c += 2) {
      a0 += (double)wp[c]  *(double)t1[c*16 + t];
      a1 += (double)wp[c+1]*(double)t1[(c+1)*16 + t];
    }
    out[((size_t)b*64 + o)*64 + tq*16 + t] = (float)(a0 + a1 + (double)B2[o]);
  }
}

// ---- k_afp : amp/freq heads + fp64 shfl-scan prefix -> f32 P0r (mod 1) + segT (g<32);
//              veff/ncon (g==32) ----
__global__ __launch_bounds__(256) void k_afp(const float* __restrict__ hh,
    const float* __restrict__ amp_w, const float* __restrict__ amp_b,
    const float* __restrict__ freq_w, const float* __restrict__ freq_b,
    const float* __restrict__ nbuf,
    const float* __restrict__ nm_w1, const float* __restrict__ nm_b1,
    const float* __restrict__ nm_w2, const float* __restrict__ nm_b2,
    const float* __restrict__ dcw,
    float* __restrict__ P0r, float4* __restrict__ segT,
    float* __restrict__ ncon) {
  int g = blockIdx.x, b = blockIdx.y;
  int tid = threadIdx.x;
  if (g < 32) {
    int ow = tid >> 6;                         // wave -> oscillator
    int o = g*4 + ow;
    int lane = tid & 63;                       // frame j
    const float* X  = hh + (size_t)b*4096 + lane;
    const float* wa = amp_w + o*64;
    const float* wf = freq_w + o*64;
    double za = (double)amp_b[o], zf = (double)freq_b[o];
    for (int c = 0; c < 64; ++c) {
      double hv = (double)X[(size_t)c*64];
      za += (double)wa[c]*hv;
      zf += (double)wf[c]*hv;
    }
    float a = fabsf((float)za);
    double sg = 1.0/(1.0 + exp(-zf));
    float f = (float)(LOWEST_D + sg*sg*(1.0 - LOWEST_D));
    double F = (double)f;                      // inclusive scan over 64 lanes
    #pragma unroll
    for (int off = 1; off < 64; off <<= 1) {
      double n = __shfl_up(F, off);
      if (lane >= off) F += n;
    }
    double Fm1 = __shfl_up(F, 1); if (lane < 1) Fm1 = 0.0;
    double Fm2 = __shfl_up(F, 2); if (lane < 2) Fm2 = 0.0;
    float fm1 = __shfl_up(f, 1);
    float am1 = __shfl_up(a, 1);
    size_t row = ((size_t)b*128 + o)*65;
    double P = (lane == 0) ? 0.0 : 64.0*(Fm1 + Fm2);
    P0r[row + lane] = (float)(P - floor(P));   // phase mod 1 rev, f32 downstream
    segT[row + lane] = (lane == 0) ? make_float4(f, 0.f, a, 0.f)
                                   : make_float4(fm1, f - fm1, am1, a - am1);
    if (lane == 63) {
      double P64 = 64.0*(F + Fm1);
      P0r[row + 64]  = (float)(P64 - floor(P64));
      segT[row + 64] = make_float4(f, 0.f, a, 0.f);
    }
  } else {
    __shared__ double veff[64];
    if (tid < 64) {                            // veff[m] = sum_c nm_w2[0,c]*nm_w1[c,m]
      double a = 0.0;
      for (int c = 0; c < 128; ++c) a += (double)nm_w2[c]*(double)nm_w1[c*64 + tid];
      veff[tid] = a;
    }
    __syncthreads();
    if (tid < 64) {
      double beff = (double)nm_b2[0];
      for (int c = 0; c < 128; ++c) beff += (double)nm_w2[c]*(double)nm_b1[c];
      int fr = tid;
      double s0 = beff;
      for (int m = 0; m < 64; ++m) s0 += veff[m]*(double)nbuf[((size_t)b*64 + m)*64 + fr];
      ncon[b*NFRM + fr] = (float)((double)dcw[b*NFRM + fr]*s0*(1.0/512.0));
    }
  }
}

// ---- k_harm : block = (q,b): 256 samples x 128 oscillators. ALL-f32 inner loop. ----
__global__ __launch_bounds__(256) void k_harm(const float* __restrict__ P0r,
                                              const float4* __restrict__ segT,
                                              const float* __restrict__ nc,
                                              float* __restrict__ outp) {
  int q = blockIdx.x;                          // 0..63
  int b = blockIdx.y;
  int tid = threadIdx.x;
  __shared__ float  P0s[256];                  // [half][osc]
  __shared__ float4 segs[256];
  int half = tid >> 7;
  int osc  = tid & 127;
  {
    size_t row = ((size_t)b*128 + osc)*65 + (q + half);
    P0s[tid]  = P0r[row];
    segs[tid] = segT[row];
  }
  __syncthreads();

  int j = q + half;
  int s = q*256 + tid;
  int r = (j == 0) ? s : (s - (256*j - 128));
  float w0 = (j == 0 || j == 64) ? 0.f : (1.f/512.f);
  float rp = (float)(r + 1);
  float c1 = rp * 0.5f;
  float c2 = (rp*w0 + (float)r*rp*(1.f/512.f)) * 0.5f;   // exact in f32
  float wr = w0 + (float)r*(1.f/256.f);

  const float*  P0p = P0s + half*128;
  const float4* sp  = segs + half*128;
  float acc = 0.f;
  #pragma unroll 4
  for (int o = 0; o < 128; ++o) {
    float4 sg = sp[o];                         // {f_lo, df, a_lo, da} uniform broadcast
    float rev = fmaf(c2, sg.y, fmaf(c1, sg.x, P0p[o]));
    rev = rev - floorf(rev);
    float sv = __builtin_amdgcn_sinf(rev);     // sin(2*pi*x)
    float am = fmaf(sg.w, wr, sg.z);
    acc = fmaf(sv, am, acc);
  }
  float ns = nc[b*NFRM + q] + ((q > 0) ? nc[b*NFRM + q - 1] : 0.f);
  outp[(size_t)b*NSMP + s] = acc + ns;
}

// ---------------------------------------------------------------------------
extern "C" void kernel_launch(void* const* d_in, const int* in_sizes, int n_in,
                              void* d_out, int out_size, void* d_ws, size_t ws_size,
                              hipStream_t stream) {
  (void)in_sizes; (void)n_in; (void)out_size; (void)ws_size;
  const float* x      = (const float*)d_in[0];
  const float* lin_w  = (const float*)d_in[1];
  const float* lin_b  = (const float*)d_in[2];
  const float* up_w0  = (const float*)d_in[3];
  const float* up_b0  = (const float*)d_in[4];
  const float* up_w1  = (const float*)d_in[5];
  const float* up_b1  = (const float*)d_in[6];
  const float* up_w2  = (const float*)d_in[7];
  const float* up_b2  = (const float*)d_in[8];
  const float* up_w3  = (const float*)d_in[9];
  const float* up_b3  = (const float*)d_in[10];
  const float* fin_w  = (const float*)d_in[11];
  const float* fin_b  = (const float*)d_in[12];
  const float* hw1    = (const float*)d_in[13];
  const float* hb1    = (const float*)d_in[14];
  const float* hw2    = (const float*)d_in[15];
  const float* hb2    = (const float*)d_in[16];
  const float* tw1    = (const float*)d_in[17];
  const float* tb1    = (const float*)d_in[18];
  const float* tw2    = (const float*)d_in[19];
  const float* tb2    = (const float*)d_in[20];
  const float* amp_w  = (const float*)d_in[21];
  const float* amp_b  = (const float*)d_in[22];
  const float* freq_w = (const float*)d_in[23];
  const float* freq_b = (const float*)d_in[24];
  const float* nm_w1  = (const float*)d_in[25];
  const float* nm_b1  = (const float*)d_in[26];
  const float* nm_w2  = (const float*)d_in[27];
  const float* nm_b2  = (const float*)d_in[28];
  const float* noise  = (const float*)d_in[29];

  float* ws = (float*)d_ws;
  float* buf0  = ws;                        // 262144 floats
  float* buf1  = ws + 262144;               // 262144
  float* hnorm = ws + 524288;               // 131072
  float* hh    = ws + 655360;               // 131072
  float* nbuf  = ws + 786432;               // 131072
  float* ncon  = ws + 917504;               // 2048
  float* dcw   = ws + 919552;               // 2048
  double* kmatg = (double*)(ws + 921600);   // 2560 doubles (byte off %8==0)
  float* P0r   = ws + 926720;               // 4096*65 floats
  float4* segT = (float4*)(ws + 1192960);   // 4096*65 float4 (byte off %16==0)

  // upconv chain buffers (ping-pong, regions dead before reuse):
  float* u16  = buf1;                       // (B,128,16) = 65536
  float* u32  = buf0;                       // (B,128,32) = 131072
  float* u64b = buf1;                       // (B,128,64) = 262144 (u16 dead)
  float* y4   = buf0;                       // (B,128,64) = 262144 (u32 dead)

  k_A   <<<dim3(NB, 21), 256, 0, stream>>>(x, lin_w, lin_b, up_w0, up_b0, u16,
                                           noise, dcw, kmatg);
  k_B   <<<dim3(NB, 8), 256, 0, stream>>>(u16, up_w1, up_b1, u32, kmatg);
  k_C   <<<dim3(NB, 8), 256, 0, stream>>>(u32, up_w2, up_b2, u64b, kmatg);
  k_D   <<<dim3(NB,16), 256, 0, stream>>>(u64b, up_w3, up_b3, y4);
  k_s4n <<<dim3(NB, 8), 256, 0, stream>>>(y4, fin_w, fin_b, hnorm);
  k_mm12<<<dim3(4, NB, 2), 256, 0, stream>>>(hnorm, hw1, hb1, hw2, hb2,
                                             tw1, tb1, tw2, tb2, hh, nbuf);
  k_afp <<<dim3(33, NB), 256, 0, stream>>>(hh, amp_w, amp_b, freq_w, freq_b,
                                           nbuf, nm_w1, nm_b1, nm_w2, nm_b2,
                                           dcw, P0r, segT, ncon);
  k_harm<<<dim3(64, NB), 256, 0, stream>>>(P0r, segT, ncon, (float*)d_out);
}